// Round 19
// baseline (580.683 us; speedup 1.0000x reference)
//
#include <hip/hip_runtime.h>
#include <math.h>

typedef _Float16 half_t;
typedef half_t h8v __attribute__((ext_vector_type(8)));
typedef half_t h4v __attribute__((ext_vector_type(4)));
typedef float f32x4 __attribute__((ext_vector_type(4)));

namespace {
constexpr int DIMC = 192;
constexpr int NB = 4;
constexpr int HH = 128, WW = 128;
constexpr int HW = HH * WW;              // 16384
constexpr int NH = 8, HD = 24;
constexpr int FP = 80;                   // padded kx width (65 valid)
constexpr long LT_PART = 128L * 192 * FP;          // 1,966,080
constexpr long LT_B    = 2 * LT_PART;              // 3,932,160
constexpr long LT_ROW  = 192L * FP;                // 15360
constexpr long XB  = 192L * HW;                    // 3,145,728
constexpr long CB0 = 0;
constexpr long CB1 = 15728640;
constexpr long OFF_T1 = 37748736;        // conv tmp / out1 / stage-1 gram partials
constexpr long OFF_Q2 = 50331648;        // q2
constexpr long OFF_S  = 62914560;        // small region
constexpr long OFF_KT = 0;               // kv2 pre-dw tmp / stage-2 gram partials
constexpr long OFF_KF = 25165824;        // kv2 final  [25.1M..50.3M) — overlaps OFF_T1!
constexpr long OFF_O2 = 0;               // out2 tmp
constexpr int  GSL = 64;                 // gram l-slices (256 l each)
constexpr long SM_INVQ1 = OFF_S;                // 768
constexpr long SM_INVK1 = OFF_S + 768;          // 768
constexpr long SM_INVQ2 = OFF_S + 1536;         // 768
constexpr long SM_INVK2 = OFF_S + 2304;         // 768
constexpr long SM_ATT   = OFF_S + 3072;         // 18,432
constexpr long H0       = OFF_S + 168960;       // fp16 pool (float units)
constexpr long H_WQKV = H0;                     // 110,592 h
constexpr long H_WF   = H0 + 55296;             // 73,728 h
constexpr long H_W1   = H0 + 92160;             // 147,456 h
constexpr long H_W2   = H0 + 165888;            // 147,456 h
constexpr long H_PRJ  = H0 + 239616;            // 36,864 h
constexpr long H_B2   = H0 + 258048;            // 65,536 h
constexpr long H_B3   = H0 + 290816;            // 65,536 h
constexpr long H_B1T  = H0 + 323584;            // 160x128 h
constexpr long H_B4T  = H0 + 333824;            // 128x160 h
constexpr float PI2 = 6.283185307179586476f;
}

// ================= init: fp16 weight/basis materialization =================
__global__ void cvt16_k(const float* __restrict__ in, half_t* __restrict__ o, int n) {
    int i = blockIdx.x * 256 + threadIdx.x;
    if (i < n) o[i] = (half_t)in[i];
}
__global__ void initB1t_k(half_t* __restrict__ B) {      // [160 j][128 k]
    int idx = blockIdx.x * 256 + threadIdx.x;
    if (idx >= 160 * 128) return;
    int j = idx / 128, k = idx % 128;
    float v = 0.f;
    if (j < 65) v = cosf(PI2 * ((k * j) & 127) / 128.f) * (1.f / 128.f);
    else if (j >= 80 && j < 145) v = -sinf(PI2 * ((k * (j - 80)) & 127) / 128.f) * (1.f / 128.f);
    B[idx] = (half_t)v;
}
__global__ void initB2h_k(half_t* __restrict__ B) {      // [256 m][256 c]
    int idx = blockIdx.x * 256 + threadIdx.x;
    int m = idx >> 8, cin = idx & 255;
    int pd = m >> 7, ky = m & 127;
    int ps = cin >> 7, y = cin & 127;
    float c, s; sincosf(PI2 * ((ky * y) & 127) / 128.f, &s, &c);
    float v = (pd == 0) ? (ps == 0 ? c : s) : (ps == 0 ? -s : c);
    B[idx] = (half_t)v;
}
__global__ void initB3h_k(half_t* __restrict__ B) {      // [256 m][256 c]
    int idx = blockIdx.x * 256 + threadIdx.x;
    int m = idx >> 8, cin = idx & 255;
    int pd = m >> 7, y = m & 127;
    int ps = cin >> 7, ky = cin & 127;
    float c, s; sincosf(PI2 * ((y * ky) & 127) / 128.f, &s, &c);
    float v = (pd == 0) ? (ps == 0 ? c : -s) : (ps == 0 ? s : c);
    B[idx] = (half_t)v;
}
__global__ void initB4t_k(half_t* __restrict__ B) {      // [128 j][160 k]
    int idx = blockIdx.x * 256 + threadIdx.x;
    if (idx >= 128 * 160) return;
    int j = idx / 160, k = idx % 160;
    float v = 0.f;
    if (k < 80) {
        if (k == 0) v = 1.f / 128.f;
        else if (k < 64) v = 2.f * cosf(PI2 * ((k * j) & 127) / 128.f) / 128.f;
        else if (k == 64) v = cosf(PI2 * ((64 * j) & 127) / 128.f) / 128.f;
    } else {
        int kx = k - 80;
        if (kx >= 1 && kx < 64) v = -2.f * sinf(PI2 * ((kx * j) & 127) / 128.f) / 128.f;
    }
    B[idx] = (half_t)v;
}
__global__ void fusew_k(const float* __restrict__ wkv, const float* __restrict__ wproj,
                        half_t* __restrict__ wf) {
    int o = blockIdx.x, c = threadIdx.x;
    float acc = 0.f;
    for (int m = 0; m < 192; ++m) acc += wkv[o * 192 + m] * wproj[m * 192 + c];
    wf[o * 192 + c] = (half_t)acc;
}

// ================= KCV: 1x1 conv, X staged once, W direct from global ========
template<int NW>
__global__ __launch_bounds__(NW * 64) void kcv(
    const half_t* __restrict__ W, const float* __restrict__ X, long xB,
    float* __restrict__ out, long oB) {
    __shared__ __align__(16) half_t S[6 * 64 * 40];     // 30720 B
    const int t = threadIdx.x;
    const long p0 = (long)blockIdx.x * 64;
    const long xb = (long)blockIdx.y * xB;
    const long ob = (long)blockIdx.y * oB;
    const int lane = t & 63, wv = t >> 6;
    const int fr = lane & 15, fg = lane >> 4;
    {
        const int sp = t & 63;
        const int g = t >> 6;
        const float* gp = X + xb + p0 + sp;
        for (int grp = g; grp < 48; grp += NW) {
            int ci0 = grp * 4;
            h4v h;
#pragma unroll
            for (int j = 0; j < 4; ++j) h[j] = (half_t)gp[(long)(ci0 + j) * HW];
            *(h4v*)&S[((ci0 >> 5) * 64 + sp) * 40 + (ci0 & 31)] = h;
        }
    }
    __syncthreads();
    f32x4 acc[3][4];
#pragma unroll
    for (int m = 0; m < 3; ++m)
#pragma unroll
        for (int n = 0; n < 4; ++n) acc[m][n] = {0.f, 0.f, 0.f, 0.f};
    for (int k0 = 0; k0 < 192; k0 += 32) {
        const int s = k0 >> 5;
        h8v a[3], bb[4];
#pragma unroll
        for (int m = 0; m < 3; ++m)
            a[m] = *(const h8v*)(W + (long)(wv * 48 + m * 16 + fr) * 192 + k0 + fg * 8);
#pragma unroll
        for (int n = 0; n < 4; ++n)
            bb[n] = *(const h8v*)&S[(s * 64 + n * 16 + fr) * 40 + fg * 8];
#pragma unroll
        for (int m = 0; m < 3; ++m)
#pragma unroll
            for (int n = 0; n < 4; ++n)
                acc[m][n] = __builtin_amdgcn_mfma_f32_16x16x32_f16(a[m], bb[n], acc[m][n], 0, 0, 0);
    }
#pragma unroll
    for (int m = 0; m < 3; ++m)
#pragma unroll
        for (int i = 0; i < 4; ++i) {
            int o = wv * 48 + m * 16 + fg * 4 + i;
            float* row = out + ob + (long)o * HW + p0;
#pragma unroll
            for (int n = 0; n < 4; ++n) row[n * 16 + fr] = acc[m][n][i];
        }
}

// ================= K2BIG: 256-o column-DFT GEMM, X staged once ===============
// IN16/OUT16: fp16 element type on input/output (same layout, same indices).
template<int IN16, int OUT16>
__global__ __launch_bounds__(256) void k2big(
    const half_t* __restrict__ B16,           // [256 o][256 k] fp16
    const void* __restrict__ Xv, void* __restrict__ outv) {
    __shared__ __align__(16) half_t Xh[8 * 64 * 40];    // 40 KB
    const int t = threadIdx.x;
    const long p0 = (long)blockIdx.x * 64;
    const long xb = (long)blockIdx.y * LT_B;
    const int lane = t & 63, wv = t >> 6;
    const int fr = lane & 15, fg = lane >> 4;
    {
        const int sp = t & 63;
        const int c0 = t >> 6;
#pragma unroll 8
        for (int j = 0; j < 64; ++j) {
            int ci = c0 + j * 4;
            long rb = (ci < 128) ? (long)ci * LT_ROW : (long)(ci - 128) * LT_ROW + LT_PART;
            half_t hv;
            if (IN16) hv = ((const half_t*)Xv)[xb + p0 + sp + rb];
            else      hv = (half_t)((const float*)Xv)[xb + p0 + sp + rb];
            Xh[((ci >> 5) * 64 + sp) * 40 + (ci & 31)] = hv;
        }
    }
    __syncthreads();
    f32x4 acc[4][4];
#pragma unroll
    for (int m = 0; m < 4; ++m)
#pragma unroll
        for (int n = 0; n < 4; ++n) acc[m][n] = {0.f, 0.f, 0.f, 0.f};
    for (int k0 = 0; k0 < 256; k0 += 32) {
        const int s = k0 >> 5;
        h8v a[4], bb[4];
#pragma unroll
        for (int m = 0; m < 4; ++m)
            a[m] = *(const h8v*)(B16 + (long)(wv * 64 + m * 16 + fr) * 256 + k0 + fg * 8);
#pragma unroll
        for (int n = 0; n < 4; ++n)
            bb[n] = *(const h8v*)&Xh[(s * 64 + n * 16 + fr) * 40 + fg * 8];
#pragma unroll
        for (int m = 0; m < 4; ++m)
#pragma unroll
            for (int n = 0; n < 4; ++n)
                acc[m][n] = __builtin_amdgcn_mfma_f32_16x16x32_f16(a[m], bb[n], acc[m][n], 0, 0, 0);
    }
#pragma unroll
    for (int m = 0; m < 4; ++m)
#pragma unroll
        for (int i = 0; i < 4; ++i) {
            int o = wv * 64 + m * 16 + fg * 4 + i;
            long oadr = xb + ((o < 128) ? (long)o * LT_ROW : (long)(o - 128) * LT_ROW + LT_PART);
#pragma unroll
            for (int n = 0; n < 4; ++n) {
                long idx = oadr + p0 + n * 16 + fr;
                if (OUT16) ((half_t*)outv)[idx] = (half_t)acc[m][n][i];
                else       ((float*)outv)[idx]  = acc[m][n][i];
            }
        }
}

// ================= KFF4H: fused W1 -> GELU -> W2, fp16 in/out ================
__global__ __launch_bounds__(512) void kff4h(
    const half_t* __restrict__ W1, const half_t* __restrict__ W2,
    const half_t* __restrict__ X, half_t* __restrict__ out) {
    __shared__ __align__(16) half_t S[12 * 64 * 40];    // 61440 B
    const int t = threadIdx.x;
    const long p0 = (long)blockIdx.x * 64;
    const long xb = (long)blockIdx.y * LT_B;
    const int lane = t & 63, wv = t >> 6;               // 0..7
    const int fr = lane & 15, fg = lane >> 4;
    {
        const int sp = t & 63;
        const int g = t >> 6;                           // 0..7
        long pa; { long p = p0 + sp; long q = p / 80; pa = q * LT_ROW + (p - q * 80); }
        const half_t* gp = X + xb + pa;
#pragma unroll
        for (int ch = 0; ch < 12; ++ch) {
            int ci0 = ch * 32 + g * 4;
            h4v h;
#pragma unroll
            for (int j = 0; j < 4; ++j) {
                int ci = ci0 + j;
                long rb = (ci < 192) ? (long)ci * 80 : (long)(ci - 192) * 80 + LT_PART;
                h[j] = gp[rb];
            }
            *(h4v*)&S[(ch * 64 + sp) * 40 + g * 4] = h;
        }
    }
    __syncthreads();
    f32x4 acc[3][4];
#pragma unroll
    for (int m = 0; m < 3; ++m)
#pragma unroll
        for (int n = 0; n < 4; ++n) acc[m][n] = {0.f, 0.f, 0.f, 0.f};
    for (int k0 = 0; k0 < 384; k0 += 32) {
        const int s = k0 >> 5;
        h8v a[3], bb[4];
#pragma unroll
        for (int m = 0; m < 3; ++m)
            a[m] = *(const h8v*)(W1 + (long)(wv * 48 + m * 16 + fr) * 384 + k0 + fg * 8);
#pragma unroll
        for (int n = 0; n < 4; ++n)
            bb[n] = *(const h8v*)&S[(s * 64 + n * 16 + fr) * 40 + fg * 8];
#pragma unroll
        for (int m = 0; m < 3; ++m)
#pragma unroll
            for (int n = 0; n < 4; ++n)
                acc[m][n] = __builtin_amdgcn_mfma_f32_16x16x32_f16(a[m], bb[n], acc[m][n], 0, 0, 0);
    }
    __syncthreads();
#pragma unroll
    for (int m = 0; m < 3; ++m)
#pragma unroll
        for (int n = 0; n < 4; ++n) {
            int o4 = wv * 48 + m * 16 + fg * 4;
            int p = n * 16 + fr;
            h4v h;
#pragma unroll
            for (int i = 0; i < 4; ++i) {
                float v = acc[m][n][i];
                v = 0.5f * v * (1.f + erff(v * 0.70710678118654752f));
                h[i] = (half_t)v;
            }
            *(h4v*)&S[((o4 >> 5) * 64 + p) * 40 + (o4 & 31)] = h;
        }
#pragma unroll
    for (int m = 0; m < 3; ++m)
#pragma unroll
        for (int n = 0; n < 4; ++n) acc[m][n] = {0.f, 0.f, 0.f, 0.f};
    __syncthreads();
    for (int k0 = 0; k0 < 384; k0 += 32) {
        const int s = k0 >> 5;
        h8v a[3], bb[4];
#pragma unroll
        for (int m = 0; m < 3; ++m)
            a[m] = *(const h8v*)(W2 + (long)(wv * 48 + m * 16 + fr) * 384 + k0 + fg * 8);
#pragma unroll
        for (int n = 0; n < 4; ++n)
            bb[n] = *(const h8v*)&S[(s * 64 + n * 16 + fr) * 40 + fg * 8];
#pragma unroll
        for (int m = 0; m < 3; ++m)
#pragma unroll
            for (int n = 0; n < 4; ++n)
                acc[m][n] = __builtin_amdgcn_mfma_f32_16x16x32_f16(a[m], bb[n], acc[m][n], 0, 0, 0);
    }
    long pe[4];
#pragma unroll
    for (int n = 0; n < 4; ++n) {
        long p = p0 + n * 16 + fr;
        long q = p / 80; pe[n] = q * LT_ROW + (p - q * 80);
    }
#pragma unroll
    for (int m = 0; m < 3; ++m)
#pragma unroll
        for (int i = 0; i < 4; ++i) {
            int o = wv * 48 + m * 16 + fg * 4 + i;
            long oadr = xb + ((o < 192) ? (long)o * 80 : (long)(o - 192) * 80 + LT_PART);
#pragma unroll
            for (int n = 0; n < 4; ++n) out[oadr + pe[n]] = (half_t)acc[m][n][i];
        }
}

// ================= K1M: fp32-data x fp16-basis MFMA GEMM (k-contiguous A) ====
// OUT16: store output as fp16 (same layout/indices).
template<int NF, int NORM, int OUT16>
__global__ __launch_bounds__(256) void k1m(
    const float* __restrict__ A, long aBatch, long aC, long aRow, int aSplit, long aHiOff, int K,
    const uint* __restrict__ Bt32,
    void* __restrict__ outv, long oBatch, long oC, long oRow, int oSplit, long oHiOff,
    float* __restrict__ inv) {
    __shared__ __align__(16) half_t Ah[128 * 40];
    __shared__ __align__(16) half_t Bh[160 * 40];
    const int t = threadIdx.x;
    const long ab = (long)blockIdx.z * aBatch + (long)blockIdx.x * aC;
    const long ob = (long)blockIdx.z * oBatch + (long)blockIdx.x * oC;
    const int N = NF * 32;
    const int lane = t & 63, wv = t >> 6;
    const int wm = wv >> 1, wn = wv & 1;
    const int fr = lane & 15, fg = lane >> 4;
    const int sr = t >> 1, shalf = t & 1;
    const int Kw = K >> 1;
    f32x4 acc[4][NF];
#pragma unroll
    for (int m = 0; m < 4; ++m)
#pragma unroll
        for (int n = 0; n < NF; ++n) acc[m][n] = {0.f, 0.f, 0.f, 0.f};
    for (int k0 = 0; k0 < K; k0 += 32) {
        __syncthreads();
        {
            int cb = k0 + shalf * 16;
            long rb = (cb < aSplit) ? (long)cb : (long)(cb - aSplit) + aHiOff;
            const float* g = A + ab + (long)sr * aRow + rb;
            float4 v0 = *(const float4*)g;
            float4 v1 = *(const float4*)(g + 4);
            float4 v2 = *(const float4*)(g + 8);
            float4 v3 = *(const float4*)(g + 12);
            h8v h0, h1;
            h0[0] = (half_t)v0.x; h0[1] = (half_t)v0.y; h0[2] = (half_t)v0.z; h0[3] = (half_t)v0.w;
            h0[4] = (half_t)v1.x; h0[5] = (half_t)v1.y; h0[6] = (half_t)v1.z; h0[7] = (half_t)v1.w;
            h1[0] = (half_t)v2.x; h1[1] = (half_t)v2.y; h1[2] = (half_t)v2.z; h1[3] = (half_t)v2.w;
            h1[4] = (half_t)v3.x; h1[5] = (half_t)v3.y; h1[6] = (half_t)v3.z; h1[7] = (half_t)v3.w;
            *(h8v*)&Ah[sr * 40 + shalf * 16] = h0;
            *(h8v*)&Ah[sr * 40 + shalf * 16 + 8] = h1;
        }
        for (int j = t; j < N * 16; j += 256) {
            int n = j >> 4, kw = j & 15;
            *(uint*)&Bh[n * 40 + kw * 2] = Bt32[(long)n * Kw + (k0 >> 1) + kw];
        }
        __syncthreads();
        h8v a[4], bb[NF];
#pragma unroll
        for (int m = 0; m < 4; ++m) a[m] = *(const h8v*)&Ah[(wm * 64 + m * 16 + fr) * 40 + fg * 8];
#pragma unroll
        for (int n = 0; n < NF; ++n) bb[n] = *(const h8v*)&Bh[(wn * NF * 16 + n * 16 + fr) * 40 + fg * 8];
#pragma unroll
        for (int m = 0; m < 4; ++m)
#pragma unroll
            for (int n = 0; n < NF; ++n)
                acc[m][n] = __builtin_amdgcn_mfma_f32_16x16x32_f16(a[m], bb[n], acc[m][n], 0, 0, 0);
    }
#pragma unroll
    for (int m = 0; m < 4; ++m)
#pragma unroll
        for (int i = 0; i < 4; ++i) {
            int r = wm * 64 + m * 16 + fg * 4 + i;
            long rbase = ob + (long)r * oRow;
#pragma unroll
            for (int n = 0; n < NF; ++n) {
                int j = wn * NF * 16 + n * 16 + fr;
                long jm = (j < oSplit) ? (long)j : (long)(j - oSplit) + oHiOff;
                if (OUT16) ((half_t*)outv)[rbase + jm] = (half_t)acc[m][n][i];
                else       ((float*)outv)[rbase + jm]  = acc[m][n][i];
            }
        }
    if (NORM) {
        float ss = 0.f;
#pragma unroll
        for (int m = 0; m < 4; ++m)
#pragma unroll
            for (int n = 0; n < NF; ++n)
#pragma unroll
                for (int i = 0; i < 4; ++i) ss += acc[m][n][i] * acc[m][n][i];
        __syncthreads();
        float* red = (float*)Ah;
        red[t] = ss;
        __syncthreads();
        for (int st = 128; st > 0; st >>= 1) {
            if (t < st) red[t] += red[t + st];
            __syncthreads();
        }
        if (t == 0) inv[(long)blockIdx.z * 192 + blockIdx.x] = 1.f / fmaxf(sqrtf(red[0]), 1e-12f);
    }
}

// ---------- depthwise 3x3, pad 1: one block per (channel, batch) plane ----------
__global__ __launch_bounds__(256) void dw3_k(
    const float* __restrict__ in, long inBatch,
    const float* __restrict__ w9,
    float* __restrict__ out, long outBatch,
    int normCnt, float* __restrict__ inv) {
    const int c = blockIdx.x, b = blockIdx.y;
    const int t = threadIdx.x;
    const float* ip = in + (long)b * inBatch + (long)c * HW;
    float* op = out + (long)b * outBatch + (long)c * HW;
    const float* wp = w9 + c * 9;
    const float w0 = wp[0], w1 = wp[1], w2 = wp[2];
    const float w3 = wp[3], w4 = wp[4], w5 = wp[5];
    const float w6 = wp[6], w7 = wp[7], w8 = wp[8];
    const int tx = t & 31;
    const int x0 = tx * 4;
    const int y0 = (t >> 5) * 16;
    const bool lx = (tx > 0), rx = (tx < 31);
    float Ar[6], Br[6], Cr[6];
#define LOADROW(Y, R) do { \
        const float* _p = ip + (Y) * 128 + x0; \
        float4 _v = *(const float4*)_p; \
        R[1] = _v.x; R[2] = _v.y; R[3] = _v.z; R[4] = _v.w; \
        R[0] = lx ? _p[-1] : 0.f; \
        R[5] = rx ? _p[4] : 0.f; } while (0)
    if (y0 == 0) { Ar[0]=Ar[1]=Ar[2]=Ar[3]=Ar[4]=Ar[5]=0.f; }
    else LOADROW(y0 - 1, Ar);
    LOADROW(y0, Br);
    float ss = 0.f;
#pragma unroll
    for (int i = 0; i < 16; ++i) {
        int y = y0 + i;
        if (y + 1 < 128) { LOADROW(y + 1, Cr); }
        else { Cr[0]=Cr[1]=Cr[2]=Cr[3]=Cr[4]=Cr[5]=0.f; }
        float o0 = Ar[0]*w0 + Ar[1]*w1 + Ar[2]*w2
                 + Br[0]*w3 + Br[1]*w4 + Br[2]*w5
                 + Cr[0]*w6 + Cr[1]*w7 + Cr[2]*w8;
        float o1 = Ar[1]*w0 + Ar[2]*w1 + Ar[3]*w2
                 + Br[1]*w3 + Br[2]*w4 + Br[3]*w5
                 + Cr[1]*w6 + Cr[2]*w7 + Cr[3]*w8;
        float o2 = Ar[2]*w0 + Ar[3]*w1 + Ar[4]*w2
                 + Br[2]*w3 + Br[3]*w4 + Br[4]*w5
                 + Cr[2]*w6 + Cr[3]*w7 + Cr[4]*w8;
        float o3 = Ar[3]*w0 + Ar[4]*w1 + Ar[5]*w2
                 + Br[3]*w3 + Br[4]*w4 + Br[5]*w5
                 + Cr[3]*w6 + Cr[4]*w7 + Cr[5]*w8;
        *(float4*)(op + y * 128 + x0) = make_float4(o0, o1, o2, o3);
        ss += o0*o0 + o1*o1 + o2*o2 + o3*o3;
#pragma unroll
        for (int j = 0; j < 6; ++j) { Ar[j] = Br[j]; Br[j] = Cr[j]; }
    }
#undef LOADROW
    if (normCnt > 0 && c < normCnt) {
        __shared__ float red[256];
        red[t] = ss;
        __syncthreads();
        for (int st = 128; st > 0; st >>= 1) {
            if (t < st) red[t] += red[t + st];
            __syncthreads();
        }
        if (t == 0) inv[(long)b * 192 + c] = 1.f / fmaxf(sqrtf(red[0]), 1e-12f);
    }
}

// ================= fp32 Gram, slice-parallel =================
__global__ __launch_bounds__(576) void gramf_k(
    const float* __restrict__ q, long qB,
    const float* __restrict__ k, long kB,
    float* __restrict__ gp) {
    __shared__ float qs[HD][260];
    __shared__ float ks[HD][260];
    const int bn = blockIdx.x, ls = blockIdx.y;
    const int b = bn >> 3, n = bn & 7;
    const int t = threadIdx.x;
    const int l0 = ls * 256;
    const float* qp = q + (long)b * qB + (long)(n * HD) * HW + l0;
    const float* kp = k + (long)b * kB + (long)(n * HD) * HW + l0;
    for (int idx = t; idx < HD * 64; idx += 576) {
        int row = idx >> 6, c4 = (idx & 63) * 4;
        *(float4*)&qs[row][c4] = *(const float4*)(qp + (long)row * HW + c4);
        *(float4*)&ks[row][c4] = *(const float4*)(kp + (long)row * HW + c4);
    }
    __syncthreads();
    const int d = t / 24, e = t - d * 24;
    float acc = 0.f;
#pragma unroll 8
    for (int j = 0; j < 256; j += 4) {
        float4 a = *(const float4*)&qs[d][j];
        float4 bb = *(const float4*)&ks[e][j];
        acc += a.x * bb.x + a.y * bb.y + a.z * bb.z + a.w * bb.w;
    }
    gp[((long)bn * 576 + t) * GSL + ls] = acc;
}

// ---------- slice-sum + normalize + temperature + softmax ----------
__global__ __launch_bounds__(256) void softmax_k(
    const float* __restrict__ gp, const float* __restrict__ invq,
    const float* __restrict__ invk, const float* __restrict__ temp,
    float* __restrict__ attn) {
    int bn = blockIdx.x;
    int b = bn >> 3, n = bn & 7;
    int t = threadIdx.x;
    __shared__ float sums[576];
    for (int idx = t; idx < 576; idx += 256) {
        const float* g = gp + ((long)bn * 576 + idx) * GSL;
        float s = 0.f;
        for (int i = 0; i < GSL; i += 4) {
            float4 v = *(const float4*)(g + i);
            s += v.x + v.y + v.z + v.w;
        }
        sums[idx] = s;
    }
    __syncthreads();
    int d = t;
    if (d >= HD) return;
    float tt = temp[n];
    float iq = invq[b * 192 + n * HD + d];
    float row[HD];
#pragma unroll
    for (int e = 0; e < HD; ++e)
        row[e] = sums[d * HD + e] * iq * invk[b * 192 + n * HD + e] * tt;
    float m = row[0];
#pragma unroll
    for (int e = 1; e < HD; ++e) m = fmaxf(m, row[e]);
    float ssum = 0.f;
#pragma unroll
    for (int e = 0; e < HD; ++e) { row[e] = expf(row[e] - m); ssum += row[e]; }
    float is = 1.f / ssum;
#pragma unroll
    for (int e = 0; e < HD; ++e) attn[(long)bn * 576 + d * HD + e] = row[e] * is;
}

// ---------- out[d,p] = sum_e attn[d,e] * v[e,p] ----------
__global__ void attnapply_k(const float* __restrict__ attn, const float* __restrict__ v,
                            long vB, float* __restrict__ out, long outB) {
    int p = blockIdx.x * 256 + threadIdx.x;
    int bn = blockIdx.y;
    int b = bn >> 3, n = bn & 7;
    __shared__ float a[576];
    for (int i = threadIdx.x; i < 576; i += 256) a[i] = attn[(long)bn * 576 + i];
    __syncthreads();
    const float* vp = v + (long)b * vB + (long)(n * HD) * HW + p;
    float acc[HD];
#pragma unroll
    for (int d = 0; d < HD; ++d) acc[d] = 0.f;
    for (int e = 0; e < HD; ++e) {
        float vv = vp[(long)e * HW];
#pragma unroll
        for (int d = 0; d < HD; ++d) acc[d] += a[d * HD + e] * vv;
    }
    float* op = out + (long)b * outB + (long)(n * HD) * HW + p;
#pragma unroll
    for (int d = 0; d < HD; ++d) op[(long)d * HW] = acc[d];
}

extern "C" void kernel_launch(void* const* d_in, const int* in_sizes, int n_in,
                              void* d_out, int out_size, void* d_ws, size_t ws_size,
                              hipStream_t stream) {
    const float* x        = (const float*)d_in[0];
    const float* w_qkv1   = (const float*)d_in[1];
    const float* w_qkv1dw = (const float*)d_in[2];
    const float* w_proj1  = (const float*)d_in[3];
    const float* w_fdfp1  = (const float*)d_in[4];
    const float* w_fdfp2  = (const float*)d_in[5];
    const float* w_kv2    = (const float*)d_in[6];
    const float* w_kv2dw  = (const float*)d_in[7];
    const float* w_proj2  = (const float*)d_in[8];
    const float* temp     = (const float*)d_in[9];
    float* out = (float*)d_out;
    float* ws  = (float*)d_ws;
    dim3 blk(256);
    const int BIG = 1 << 20;

    // ---- init fp16 weights/bases ----
    cvt16_k<<<432, blk, 0, stream>>>(w_qkv1, (half_t*)(ws + H_WQKV), 110592);
    cvt16_k<<<576, blk, 0, stream>>>(w_fdfp1, (half_t*)(ws + H_W1), 147456);
    cvt16_k<<<576, blk, 0, stream>>>(w_fdfp2, (half_t*)(ws + H_W2), 147456);
    cvt16_k<<<144, blk, 0, stream>>>(w_proj2, (half_t*)(ws + H_PRJ), 36864);
    initB1t_k<<<80, blk, 0, stream>>>((half_t*)(ws + H_B1T));
    initB2h_k<<<256, blk, 0, stream>>>((half_t*)(ws + H_B2));
    initB3h_k<<<256, blk, 0, stream>>>((half_t*)(ws + H_B3));
    initB4t_k<<<80, blk, 0, stream>>>((half_t*)(ws + H_B4T));
    fusew_k<<<384, 192, 0, stream>>>(w_kv2, w_proj1, (half_t*)(ws + H_WF));

    // ---- fdfp(x) -> q2 (+ fused q2 norms) ----
    // rowfwd: x (fp32) -> CB0 as fp16
    k1m<5, 0, 1><<<dim3(192, 1, 4), blk, 0, stream>>>(
        x, XB, (long)HW, 128L, BIG, 0L, 128,
        (const uint*)(ws + H_B1T),
        (void*)(ws + CB0), LT_B, (long)FP, LT_ROW, 80, LT_PART, nullptr);
    // colfwd: fp16 CB0 -> fp16 CB1
    k2big<1, 1><<<dim3(240, 4), blk, 0, stream>>>(
        (const half_t*)(ws + H_B2), (const void*)(ws + CB0), (void*)(ws + CB1));
    // FFN: fp16 CB1 -> fp16 CB0
    kff4h<<<dim3(160, 4), 512, 0, stream>>>(
        (const half_t*)(ws + H_W1), (const half_t*)(ws + H_W2),
        (const half_t*)(ws + CB1), (half_t*)(ws + CB0));
    // colinv: fp16 CB0 -> fp32 CB1 (feeds rowinv's float4 staging)
    k2big<1, 0><<<dim3(240, 4), blk, 0, stream>>>(
        (const half_t*)(ws + H_B3), (const void*)(ws + CB0), (void*)(ws + CB1));
    // rowinv: fp32 CB1 -> q2 fp32 (+ norms)
    k1m<4, 1, 0><<<dim3(192, 1, 4), blk, 0, stream>>>(
        ws + CB1, LT_B, (long)FP, LT_ROW, 80, LT_PART, 160,
        (const uint*)(ws + H_B4T),
        (void*)(ws + OFF_Q2), XB, (long)HW, 128L, BIG, 0L, ws + SM_INVQ2);

    // ---- stage 1: qkv = dw3(kcv(x)) in 3 chunks (+ fused q1/k1 norms) ----
    for (int ch = 0; ch < 3; ++ch) {
        kcv<4><<<dim3(256, 4), 256, 0, stream>>>(
            (const half_t*)(ws + H_WQKV) + (long)ch * 192 * 192,
            x, XB, ws + OFF_T1, XB);
        dw3_k<<<dim3(192, 4), blk, 0, stream>>>(
            ws + OFF_T1, XB, w_qkv1dw + ch * 192 * 9,
            ws + (long)ch * 192 * HW, (long)576 * HW,
            ch == 2 ? 0 : 192,
            ch == 0 ? ws + SM_INVQ1 : ws + SM_INVK1);
    }
    // stage-1 partials at OFF_T1: qkv [0..37.7M) live, OFF_T1 [37.7M..] free.
    gramf_k<<<dim3(32, GSL), 576, 0, stream>>>(
        ws, (long)576 * HW, ws + (long)192 * HW, (long)576 * HW, ws + OFF_T1);
    softmax_k<<<32, blk, 0, stream>>>(ws + OFF_T1, ws + SM_INVQ1, ws + SM_INVK1, temp, ws + SM_ATT);
    attnapply_k<<<dim3(64, 32), blk, 0, stream>>>(
        ws + SM_ATT, ws + (long)384 * HW, (long)576 * HW, ws + OFF_T1, XB);

    // ---- kv2 = dw3(kcv(out1, Wf)) (+ fused k2 norms) ----
    kcv<8><<<dim3(256, 4), 512, 0, stream>>>(
        (const half_t*)(ws + H_WF), ws + OFF_T1, XB, ws + OFF_KT, (long)384 * HW);
    dw3_k<<<dim3(384, 4), blk, 0, stream>>>(
        ws + OFF_KT, (long)384 * HW, w_kv2dw, ws + OFF_KF, (long)384 * HW,
        192, ws + SM_INVK2);

    // ---- stage 2 attention ----
    // partials at ws[0..1.18M): kv2 pre-dw tmp region, dead after dw3.
    // (NOT OFF_T1 — that aliases kv2 batch 2, the r6-r8 corruption.)
    gramf_k<<<dim3(32, GSL), 576, 0, stream>>>(
        ws + OFF_Q2, XB, ws + OFF_KF, (long)384 * HW, ws + OFF_KT);
    softmax_k<<<32, blk, 0, stream>>>(ws + OFF_KT, ws + SM_INVQ2, ws + SM_INVK2, temp, ws + SM_ATT);
    attnapply_k<<<dim3(64, 32), blk, 0, stream>>>(
        ws + SM_ATT, ws + OFF_KF + (long)192 * HW, (long)384 * HW, ws + OFF_O2, XB);
    kcv<4><<<dim3(256, 4), 256, 0, stream>>>(
        (const half_t*)(ws + H_PRJ), ws + OFF_O2, XB, out, XB);
}

// Round 20
// 578.407 us; speedup vs baseline: 1.0039x; 1.0039x over previous
//
#include <hip/hip_runtime.h>
#include <math.h>

typedef _Float16 half_t;
typedef half_t h8v __attribute__((ext_vector_type(8)));
typedef half_t h4v __attribute__((ext_vector_type(4)));
typedef float f32x4 __attribute__((ext_vector_type(4)));

namespace {
constexpr int DIMC = 192;
constexpr int NB = 4;
constexpr int HH = 128, WW = 128;
constexpr int HW = HH * WW;              // 16384
constexpr int NH = 8, HD = 24;
constexpr int FP = 80;                   // padded kx width (65 valid)
constexpr long LT_PART = 128L * 192 * FP;          // 1,966,080
constexpr long LT_B    = 2 * LT_PART;              // 3,932,160
constexpr long LT_ROW  = 192L * FP;                // 15360
constexpr long XB  = 192L * HW;                    // 3,145,728
constexpr long CB0 = 0;
constexpr long CB1 = 15728640;
constexpr long OFF_T1 = 37748736;        // conv tmp / out1 / stage-1 gram partials
constexpr long OFF_Q2 = 50331648;        // q2
constexpr long OFF_S  = 62914560;        // small region
constexpr long OFF_KT = 0;               // kv2 pre-dw tmp / stage-2 gram partials
constexpr long OFF_KF = 25165824;        // kv2 final  [25.1M..50.3M) — overlaps OFF_T1!
constexpr long OFF_O2 = 0;               // out2 tmp
constexpr int  GSL = 64;                 // gram l-slices (256 l each)
constexpr long SM_INVQ1 = OFF_S;                // 768
constexpr long SM_INVK1 = OFF_S + 768;          // 768
constexpr long SM_INVQ2 = OFF_S + 1536;         // 768
constexpr long SM_INVK2 = OFF_S + 2304;         // 768
constexpr long SM_ATT   = OFF_S + 3072;         // 18,432
constexpr long H0       = OFF_S + 168960;       // fp16 pool (float units)
constexpr long H_WQKV = H0;                     // 110,592 h
constexpr long H_WF   = H0 + 55296;             // 73,728 h
constexpr long H_W1   = H0 + 92160;             // 147,456 h
constexpr long H_W2   = H0 + 165888;            // 147,456 h
constexpr long H_PRJ  = H0 + 239616;            // 36,864 h
constexpr long H_B2   = H0 + 258048;            // 65,536 h
constexpr long H_B3   = H0 + 290816;            // 65,536 h
constexpr long H_B1T  = H0 + 323584;            // 160x128 h
constexpr long H_B4T  = H0 + 333824;            // 128x160 h
constexpr float PI2 = 6.283185307179586476f;
}

// ================= init: fp16 weight/basis materialization =================
__global__ void cvt16_k(const float* __restrict__ in, half_t* __restrict__ o, int n) {
    int i = blockIdx.x * 256 + threadIdx.x;
    if (i < n) o[i] = (half_t)in[i];
}
__global__ void initB1t_k(half_t* __restrict__ B) {      // [160 j][128 k]
    int idx = blockIdx.x * 256 + threadIdx.x;
    if (idx >= 160 * 128) return;
    int j = idx / 128, k = idx % 128;
    float v = 0.f;
    if (j < 65) v = cosf(PI2 * ((k * j) & 127) / 128.f) * (1.f / 128.f);
    else if (j >= 80 && j < 145) v = -sinf(PI2 * ((k * (j - 80)) & 127) / 128.f) * (1.f / 128.f);
    B[idx] = (half_t)v;
}
__global__ void initB2h_k(half_t* __restrict__ B) {      // [256 m][256 c]
    int idx = blockIdx.x * 256 + threadIdx.x;
    int m = idx >> 8, cin = idx & 255;
    int pd = m >> 7, ky = m & 127;
    int ps = cin >> 7, y = cin & 127;
    float c, s; sincosf(PI2 * ((ky * y) & 127) / 128.f, &s, &c);
    float v = (pd == 0) ? (ps == 0 ? c : s) : (ps == 0 ? -s : c);
    B[idx] = (half_t)v;
}
__global__ void initB3h_k(half_t* __restrict__ B) {      // [256 m][256 c]
    int idx = blockIdx.x * 256 + threadIdx.x;
    int m = idx >> 8, cin = idx & 255;
    int pd = m >> 7, y = m & 127;
    int ps = cin >> 7, ky = cin & 127;
    float c, s; sincosf(PI2 * ((y * ky) & 127) / 128.f, &s, &c);
    float v = (pd == 0) ? (ps == 0 ? c : -s) : (ps == 0 ? s : c);
    B[idx] = (half_t)v;
}
__global__ void initB4t_k(half_t* __restrict__ B) {      // [128 j][160 k]
    int idx = blockIdx.x * 256 + threadIdx.x;
    if (idx >= 128 * 160) return;
    int j = idx / 160, k = idx % 160;
    float v = 0.f;
    if (k < 80) {
        if (k == 0) v = 1.f / 128.f;
        else if (k < 64) v = 2.f * cosf(PI2 * ((k * j) & 127) / 128.f) / 128.f;
        else if (k == 64) v = cosf(PI2 * ((64 * j) & 127) / 128.f) / 128.f;
    } else {
        int kx = k - 80;
        if (kx >= 1 && kx < 64) v = -2.f * sinf(PI2 * ((kx * j) & 127) / 128.f) / 128.f;
    }
    B[idx] = (half_t)v;
}
__global__ void fusew_k(const float* __restrict__ wkv, const float* __restrict__ wproj,
                        half_t* __restrict__ wf) {
    int o = blockIdx.x, c = threadIdx.x;
    float acc = 0.f;
    for (int m = 0; m < 192; ++m) acc += wkv[o * 192 + m] * wproj[m * 192 + c];
    wf[o * 192 + c] = (half_t)acc;
}

// ================= KCV: 1x1 conv, X staged once, W direct from global ========
template<int NW>
__global__ __launch_bounds__(NW * 64) void kcv(
    const half_t* __restrict__ W, const float* __restrict__ X, long xB,
    float* __restrict__ out, long oB) {
    __shared__ __align__(16) half_t S[6 * 64 * 40];     // 30720 B
    const int t = threadIdx.x;
    const long p0 = (long)blockIdx.x * 64;
    const long xb = (long)blockIdx.y * xB;
    const long ob = (long)blockIdx.y * oB;
    const int lane = t & 63, wv = t >> 6;
    const int fr = lane & 15, fg = lane >> 4;
    {
        const int sp = t & 63;
        const int g = t >> 6;
        const float* gp = X + xb + p0 + sp;
        for (int grp = g; grp < 48; grp += NW) {
            int ci0 = grp * 4;
            h4v h;
#pragma unroll
            for (int j = 0; j < 4; ++j) h[j] = (half_t)gp[(long)(ci0 + j) * HW];
            *(h4v*)&S[((ci0 >> 5) * 64 + sp) * 40 + (ci0 & 31)] = h;
        }
    }
    __syncthreads();
    f32x4 acc[3][4];
#pragma unroll
    for (int m = 0; m < 3; ++m)
#pragma unroll
        for (int n = 0; n < 4; ++n) acc[m][n] = {0.f, 0.f, 0.f, 0.f};
    for (int k0 = 0; k0 < 192; k0 += 32) {
        const int s = k0 >> 5;
        h8v a[3], bb[4];
#pragma unroll
        for (int m = 0; m < 3; ++m)
            a[m] = *(const h8v*)(W + (long)(wv * 48 + m * 16 + fr) * 192 + k0 + fg * 8);
#pragma unroll
        for (int n = 0; n < 4; ++n)
            bb[n] = *(const h8v*)&S[(s * 64 + n * 16 + fr) * 40 + fg * 8];
#pragma unroll
        for (int m = 0; m < 3; ++m)
#pragma unroll
            for (int n = 0; n < 4; ++n)
                acc[m][n] = __builtin_amdgcn_mfma_f32_16x16x32_f16(a[m], bb[n], acc[m][n], 0, 0, 0);
    }
#pragma unroll
    for (int m = 0; m < 3; ++m)
#pragma unroll
        for (int i = 0; i < 4; ++i) {
            int o = wv * 48 + m * 16 + fg * 4 + i;
            float* row = out + ob + (long)o * HW + p0;
#pragma unroll
            for (int n = 0; n < 4; ++n) row[n * 16 + fr] = acc[m][n][i];
        }
}

// ================= K2BIG: 256-o column-DFT GEMM, X staged once ===============
template<int IN16, int OUT16>
__global__ __launch_bounds__(256) void k2big(
    const half_t* __restrict__ B16,           // [256 o][256 k] fp16
    const void* __restrict__ Xv, void* __restrict__ outv) {
    __shared__ __align__(16) half_t Xh[8 * 64 * 40];    // 40 KB
    const int t = threadIdx.x;
    const long p0 = (long)blockIdx.x * 64;
    const long xb = (long)blockIdx.y * LT_B;
    const int lane = t & 63, wv = t >> 6;
    const int fr = lane & 15, fg = lane >> 4;
    {
        const int sp = t & 63;
        const int c0 = t >> 6;
#pragma unroll 8
        for (int j = 0; j < 64; ++j) {
            int ci = c0 + j * 4;
            long rb = (ci < 128) ? (long)ci * LT_ROW : (long)(ci - 128) * LT_ROW + LT_PART;
            half_t hv;
            if (IN16) hv = ((const half_t*)Xv)[xb + p0 + sp + rb];
            else      hv = (half_t)((const float*)Xv)[xb + p0 + sp + rb];
            Xh[((ci >> 5) * 64 + sp) * 40 + (ci & 31)] = hv;
        }
    }
    __syncthreads();
    f32x4 acc[4][4];
#pragma unroll
    for (int m = 0; m < 4; ++m)
#pragma unroll
        for (int n = 0; n < 4; ++n) acc[m][n] = {0.f, 0.f, 0.f, 0.f};
    for (int k0 = 0; k0 < 256; k0 += 32) {
        const int s = k0 >> 5;
        h8v a[4], bb[4];
#pragma unroll
        for (int m = 0; m < 4; ++m)
            a[m] = *(const h8v*)(B16 + (long)(wv * 64 + m * 16 + fr) * 256 + k0 + fg * 8);
#pragma unroll
        for (int n = 0; n < 4; ++n)
            bb[n] = *(const h8v*)&Xh[(s * 64 + n * 16 + fr) * 40 + fg * 8];
#pragma unroll
        for (int m = 0; m < 4; ++m)
#pragma unroll
            for (int n = 0; n < 4; ++n)
                acc[m][n] = __builtin_amdgcn_mfma_f32_16x16x32_f16(a[m], bb[n], acc[m][n], 0, 0, 0);
    }
#pragma unroll
    for (int m = 0; m < 4; ++m)
#pragma unroll
        for (int i = 0; i < 4; ++i) {
            int o = wv * 64 + m * 16 + fg * 4 + i;
            long oadr = xb + ((o < 128) ? (long)o * LT_ROW : (long)(o - 128) * LT_ROW + LT_PART);
#pragma unroll
            for (int n = 0; n < 4; ++n) {
                long idx = oadr + p0 + n * 16 + fr;
                if (OUT16) ((half_t*)outv)[idx] = (half_t)acc[m][n][i];
                else       ((float*)outv)[idx]  = acc[m][n][i];
            }
        }
}

// ================= KFF4H: fused W1 -> GELU -> W2, fp16 in/out ================
__global__ __launch_bounds__(512) void kff4h(
    const half_t* __restrict__ W1, const half_t* __restrict__ W2,
    const half_t* __restrict__ X, half_t* __restrict__ out) {
    __shared__ __align__(16) half_t S[12 * 64 * 40];    // 61440 B
    const int t = threadIdx.x;
    const long p0 = (long)blockIdx.x * 64;
    const long xb = (long)blockIdx.y * LT_B;
    const int lane = t & 63, wv = t >> 6;               // 0..7
    const int fr = lane & 15, fg = lane >> 4;
    {
        const int sp = t & 63;
        const int g = t >> 6;                           // 0..7
        long pa; { long p = p0 + sp; long q = p / 80; pa = q * LT_ROW + (p - q * 80); }
        const half_t* gp = X + xb + pa;
#pragma unroll
        for (int ch = 0; ch < 12; ++ch) {
            int ci0 = ch * 32 + g * 4;
            h4v h;
#pragma unroll
            for (int j = 0; j < 4; ++j) {
                int ci = ci0 + j;
                long rb = (ci < 192) ? (long)ci * 80 : (long)(ci - 192) * 80 + LT_PART;
                h[j] = gp[rb];
            }
            *(h4v*)&S[(ch * 64 + sp) * 40 + g * 4] = h;
        }
    }
    __syncthreads();
    f32x4 acc[3][4];
#pragma unroll
    for (int m = 0; m < 3; ++m)
#pragma unroll
        for (int n = 0; n < 4; ++n) acc[m][n] = {0.f, 0.f, 0.f, 0.f};
    for (int k0 = 0; k0 < 384; k0 += 32) {
        const int s = k0 >> 5;
        h8v a[3], bb[4];
#pragma unroll
        for (int m = 0; m < 3; ++m)
            a[m] = *(const h8v*)(W1 + (long)(wv * 48 + m * 16 + fr) * 384 + k0 + fg * 8);
#pragma unroll
        for (int n = 0; n < 4; ++n)
            bb[n] = *(const h8v*)&S[(s * 64 + n * 16 + fr) * 40 + fg * 8];
#pragma unroll
        for (int m = 0; m < 3; ++m)
#pragma unroll
            for (int n = 0; n < 4; ++n)
                acc[m][n] = __builtin_amdgcn_mfma_f32_16x16x32_f16(a[m], bb[n], acc[m][n], 0, 0, 0);
    }
    __syncthreads();
#pragma unroll
    for (int m = 0; m < 3; ++m)
#pragma unroll
        for (int n = 0; n < 4; ++n) {
            int o4 = wv * 48 + m * 16 + fg * 4;
            int p = n * 16 + fr;
            h4v h;
#pragma unroll
            for (int i = 0; i < 4; ++i) {
                float v = acc[m][n][i];
                v = 0.5f * v * (1.f + erff(v * 0.70710678118654752f));
                h[i] = (half_t)v;
            }
            *(h4v*)&S[((o4 >> 5) * 64 + p) * 40 + (o4 & 31)] = h;
        }
#pragma unroll
    for (int m = 0; m < 3; ++m)
#pragma unroll
        for (int n = 0; n < 4; ++n) acc[m][n] = {0.f, 0.f, 0.f, 0.f};
    __syncthreads();
    for (int k0 = 0; k0 < 384; k0 += 32) {
        const int s = k0 >> 5;
        h8v a[3], bb[4];
#pragma unroll
        for (int m = 0; m < 3; ++m)
            a[m] = *(const h8v*)(W2 + (long)(wv * 48 + m * 16 + fr) * 384 + k0 + fg * 8);
#pragma unroll
        for (int n = 0; n < 4; ++n)
            bb[n] = *(const h8v*)&S[(s * 64 + n * 16 + fr) * 40 + fg * 8];
#pragma unroll
        for (int m = 0; m < 3; ++m)
#pragma unroll
            for (int n = 0; n < 4; ++n)
                acc[m][n] = __builtin_amdgcn_mfma_f32_16x16x32_f16(a[m], bb[n], acc[m][n], 0, 0, 0);
    }
    long pe[4];
#pragma unroll
    for (int n = 0; n < 4; ++n) {
        long p = p0 + n * 16 + fr;
        long q = p / 80; pe[n] = q * LT_ROW + (p - q * 80);
    }
#pragma unroll
    for (int m = 0; m < 3; ++m)
#pragma unroll
        for (int i = 0; i < 4; ++i) {
            int o = wv * 48 + m * 16 + fg * 4 + i;
            long oadr = xb + ((o < 192) ? (long)o * 80 : (long)(o - 192) * 80 + LT_PART);
#pragma unroll
            for (int n = 0; n < 4; ++n) out[oadr + pe[n]] = (half_t)acc[m][n][i];
        }
}

// ================= K1BIG: row-DFT GEMM, zero LDS, zero in-loop barriers ======
// C[r][j] = sum_k A[r][kmap(k)] * Bt[j][k] per (c,b) plane; 128 rows, N=NF*32.
// A fp32, k-contiguous per 8-k group (aSplit % 8 == 0). Bt fp16 [N][K], L2-hot.
// 256 threads (4 waves); wave w owns rows [w*32, w*32+32).
template<int NF, int NORM, int OUT16, int K>
__global__ __launch_bounds__(256) void k1big(
    const float* __restrict__ A, long aBatch, long aC, long aRow, int aSplit, long aHiOff,
    const half_t* __restrict__ Bt,
    void* __restrict__ outv, long oBatch, long oC, long oRow, int oSplit, long oHiOff,
    float* __restrict__ inv) {
    const int t = threadIdx.x;
    const long ab = (long)blockIdx.y * aBatch + (long)blockIdx.x * aC;
    const long ob = (long)blockIdx.y * oBatch + (long)blockIdx.x * oC;
    const int lane = t & 63, wv = t >> 6;
    const int fr = lane & 15, fg = lane >> 4;
    constexpr int NFR = NF * 2;
    f32x4 acc[2][NFR];
#pragma unroll
    for (int m = 0; m < 2; ++m)
#pragma unroll
        for (int n = 0; n < NFR; ++n) acc[m][n] = {0.f, 0.f, 0.f, 0.f};
    for (int k0 = 0; k0 < K; k0 += 32) {
        int kk = k0 + fg * 8;
        long ka = (kk < aSplit) ? (long)kk : (long)(kk - aSplit) + aHiOff;
        h8v a[2];
#pragma unroll
        for (int m = 0; m < 2; ++m) {
            const float* g = A + ab + (long)(wv * 32 + m * 16 + fr) * aRow + ka;
            float4 v0 = *(const float4*)g;
            float4 v1 = *(const float4*)(g + 4);
            a[m][0] = (half_t)v0.x; a[m][1] = (half_t)v0.y;
            a[m][2] = (half_t)v0.z; a[m][3] = (half_t)v0.w;
            a[m][4] = (half_t)v1.x; a[m][5] = (half_t)v1.y;
            a[m][6] = (half_t)v1.z; a[m][7] = (half_t)v1.w;
        }
        h8v bb[NFR];
#pragma unroll
        for (int n = 0; n < NFR; ++n)
            bb[n] = *(const h8v*)(Bt + (long)(n * 16 + fr) * K + kk);
#pragma unroll
        for (int m = 0; m < 2; ++m)
#pragma unroll
            for (int n = 0; n < NFR; ++n)
                acc[m][n] = __builtin_amdgcn_mfma_f32_16x16x32_f16(a[m], bb[n], acc[m][n], 0, 0, 0);
    }
#pragma unroll
    for (int m = 0; m < 2; ++m)
#pragma unroll
        for (int i = 0; i < 4; ++i) {
            int r = wv * 32 + m * 16 + fg * 4 + i;
            long rbase = ob + (long)r * oRow;
#pragma unroll
            for (int n = 0; n < NFR; ++n) {
                int j = n * 16 + fr;
                long jm = (j < oSplit) ? (long)j : (long)(j - oSplit) + oHiOff;
                if (OUT16) ((half_t*)outv)[rbase + jm] = (half_t)acc[m][n][i];
                else       ((float*)outv)[rbase + jm]  = acc[m][n][i];
            }
        }
    if (NORM) {
        float ss = 0.f;
#pragma unroll
        for (int m = 0; m < 2; ++m)
#pragma unroll
            for (int n = 0; n < NFR; ++n)
#pragma unroll
                for (int i = 0; i < 4; ++i) ss += acc[m][n][i] * acc[m][n][i];
        __shared__ float red[256];
        red[t] = ss;
        __syncthreads();
        for (int st = 128; st > 0; st >>= 1) {
            if (t < st) red[t] += red[t + st];
            __syncthreads();
        }
        if (t == 0) inv[(long)blockIdx.y * 192 + blockIdx.x] = 1.f / fmaxf(sqrtf(red[0]), 1e-12f);
    }
}

// ---------- depthwise 3x3, pad 1: one block per (channel, batch) plane ----------
__global__ __launch_bounds__(256) void dw3_k(
    const float* __restrict__ in, long inBatch,
    const float* __restrict__ w9,
    float* __restrict__ out, long outBatch,
    int normCnt, float* __restrict__ inv) {
    const int c = blockIdx.x, b = blockIdx.y;
    const int t = threadIdx.x;
    const float* ip = in + (long)b * inBatch + (long)c * HW;
    float* op = out + (long)b * outBatch + (long)c * HW;
    const float* wp = w9 + c * 9;
    const float w0 = wp[0], w1 = wp[1], w2 = wp[2];
    const float w3 = wp[3], w4 = wp[4], w5 = wp[5];
    const float w6 = wp[6], w7 = wp[7], w8 = wp[8];
    const int tx = t & 31;
    const int x0 = tx * 4;
    const int y0 = (t >> 5) * 16;
    const bool lx = (tx > 0), rx = (tx < 31);
    float Ar[6], Br[6], Cr[6];
#define LOADROW(Y, R) do { \
        const float* _p = ip + (Y) * 128 + x0; \
        float4 _v = *(const float4*)_p; \
        R[1] = _v.x; R[2] = _v.y; R[3] = _v.z; R[4] = _v.w; \
        R[0] = lx ? _p[-1] : 0.f; \
        R[5] = rx ? _p[4] : 0.f; } while (0)
    if (y0 == 0) { Ar[0]=Ar[1]=Ar[2]=Ar[3]=Ar[4]=Ar[5]=0.f; }
    else LOADROW(y0 - 1, Ar);
    LOADROW(y0, Br);
    float ss = 0.f;
#pragma unroll
    for (int i = 0; i < 16; ++i) {
        int y = y0 + i;
        if (y + 1 < 128) { LOADROW(y + 1, Cr); }
        else { Cr[0]=Cr[1]=Cr[2]=Cr[3]=Cr[4]=Cr[5]=0.f; }
        float o0 = Ar[0]*w0 + Ar[1]*w1 + Ar[2]*w2
                 + Br[0]*w3 + Br[1]*w4 + Br[2]*w5
                 + Cr[0]*w6 + Cr[1]*w7 + Cr[2]*w8;
        float o1 = Ar[1]*w0 + Ar[2]*w1 + Ar[3]*w2
                 + Br[1]*w3 + Br[2]*w4 + Br[3]*w5
                 + Cr[1]*w6 + Cr[2]*w7 + Cr[3]*w8;
        float o2 = Ar[2]*w0 + Ar[3]*w1 + Ar[4]*w2
                 + Br[2]*w3 + Br[3]*w4 + Br[4]*w5
                 + Cr[2]*w6 + Cr[3]*w7 + Cr[4]*w8;
        float o3 = Ar[3]*w0 + Ar[4]*w1 + Ar[5]*w2
                 + Br[3]*w3 + Br[4]*w4 + Br[5]*w5
                 + Cr[3]*w6 + Cr[4]*w7 + Cr[5]*w8;
        *(float4*)(op + y * 128 + x0) = make_float4(o0, o1, o2, o3);
        ss += o0*o0 + o1*o1 + o2*o2 + o3*o3;
#pragma unroll
        for (int j = 0; j < 6; ++j) { Ar[j] = Br[j]; Br[j] = Cr[j]; }
    }
#undef LOADROW
    if (normCnt > 0 && c < normCnt) {
        __shared__ float red[256];
        red[t] = ss;
        __syncthreads();
        for (int st = 128; st > 0; st >>= 1) {
            if (t < st) red[t] += red[t + st];
            __syncthreads();
        }
        if (t == 0) inv[(long)b * 192 + c] = 1.f / fmaxf(sqrtf(red[0]), 1e-12f);
    }
}

// ================= fp32 Gram, slice-parallel =================
__global__ __launch_bounds__(576) void gramf_k(
    const float* __restrict__ q, long qB,
    const float* __restrict__ k, long kB,
    float* __restrict__ gp) {
    __shared__ float qs[HD][260];
    __shared__ float ks[HD][260];
    const int bn = blockIdx.x, ls = blockIdx.y;
    const int b = bn >> 3, n = bn & 7;
    const int t = threadIdx.x;
    const int l0 = ls * 256;
    const float* qp = q + (long)b * qB + (long)(n * HD) * HW + l0;
    const float* kp = k + (long)b * kB + (long)(n * HD) * HW + l0;
    for (int idx = t; idx < HD * 64; idx += 576) {
        int row = idx >> 6, c4 = (idx & 63) * 4;
        *(float4*)&qs[row][c4] = *(const float4*)(qp + (long)row * HW + c4);
        *(float4*)&ks[row][c4] = *(const float4*)(kp + (long)row * HW + c4);
    }
    __syncthreads();
    const int d = t / 24, e = t - d * 24;
    float acc = 0.f;
#pragma unroll 8
    for (int j = 0; j < 256; j += 4) {
        float4 a = *(const float4*)&qs[d][j];
        float4 bb = *(const float4*)&ks[e][j];
        acc += a.x * bb.x + a.y * bb.y + a.z * bb.z + a.w * bb.w;
    }
    gp[((long)bn * 576 + t) * GSL + ls] = acc;
}

// ---------- slice-sum + normalize + temperature + softmax ----------
__global__ __launch_bounds__(256) void softmax_k(
    const float* __restrict__ gp, const float* __restrict__ invq,
    const float* __restrict__ invk, const float* __restrict__ temp,
    float* __restrict__ attn) {
    int bn = blockIdx.x;
    int b = bn >> 3, n = bn & 7;
    int t = threadIdx.x;
    __shared__ float sums[576];
    for (int idx = t; idx < 576; idx += 256) {
        const float* g = gp + ((long)bn * 576 + idx) * GSL;
        float s = 0.f;
        for (int i = 0; i < GSL; i += 4) {
            float4 v = *(const float4*)(g + i);
            s += v.x + v.y + v.z + v.w;
        }
        sums[idx] = s;
    }
    __syncthreads();
    int d = t;
    if (d >= HD) return;
    float tt = temp[n];
    float iq = invq[b * 192 + n * HD + d];
    float row[HD];
#pragma unroll
    for (int e = 0; e < HD; ++e)
        row[e] = sums[d * HD + e] * iq * invk[b * 192 + n * HD + e] * tt;
    float m = row[0];
#pragma unroll
    for (int e = 1; e < HD; ++e) m = fmaxf(m, row[e]);
    float ssum = 0.f;
#pragma unroll
    for (int e = 0; e < HD; ++e) { row[e] = expf(row[e] - m); ssum += row[e]; }
    float is = 1.f / ssum;
#pragma unroll
    for (int e = 0; e < HD; ++e) attn[(long)bn * 576 + d * HD + e] = row[e] * is;
}

// ---------- out[d,p] = sum_e attn[d,e] * v[e,p] ----------
__global__ void attnapply_k(const float* __restrict__ attn, const float* __restrict__ v,
                            long vB, float* __restrict__ out, long outB) {
    int p = blockIdx.x * 256 + threadIdx.x;
    int bn = blockIdx.y;
    int b = bn >> 3, n = bn & 7;
    __shared__ float a[576];
    for (int i = threadIdx.x; i < 576; i += 256) a[i] = attn[(long)bn * 576 + i];
    __syncthreads();
    const float* vp = v + (long)b * vB + (long)(n * HD) * HW + p;
    float acc[HD];
#pragma unroll
    for (int d = 0; d < HD; ++d) acc[d] = 0.f;
    for (int e = 0; e < HD; ++e) {
        float vv = vp[(long)e * HW];
#pragma unroll
        for (int d = 0; d < HD; ++d) acc[d] += a[d * HD + e] * vv;
    }
    float* op = out + (long)b * outB + (long)(n * HD) * HW + p;
#pragma unroll
    for (int d = 0; d < HD; ++d) op[(long)d * HW] = acc[d];
}

extern "C" void kernel_launch(void* const* d_in, const int* in_sizes, int n_in,
                              void* d_out, int out_size, void* d_ws, size_t ws_size,
                              hipStream_t stream) {
    const float* x        = (const float*)d_in[0];
    const float* w_qkv1   = (const float*)d_in[1];
    const float* w_qkv1dw = (const float*)d_in[2];
    const float* w_proj1  = (const float*)d_in[3];
    const float* w_fdfp1  = (const float*)d_in[4];
    const float* w_fdfp2  = (const float*)d_in[5];
    const float* w_kv2    = (const float*)d_in[6];
    const float* w_kv2dw  = (const float*)d_in[7];
    const float* w_proj2  = (const float*)d_in[8];
    const float* temp     = (const float*)d_in[9];
    float* out = (float*)d_out;
    float* ws  = (float*)d_ws;
    dim3 blk(256);
    const int BIG = 1 << 20;

    // ---- init fp16 weights/bases ----
    cvt16_k<<<432, blk, 0, stream>>>(w_qkv1, (half_t*)(ws + H_WQKV), 110592);
    cvt16_k<<<576, blk, 0, stream>>>(w_fdfp1, (half_t*)(ws + H_W1), 147456);
    cvt16_k<<<576, blk, 0, stream>>>(w_fdfp2, (half_t*)(ws + H_W2), 147456);
    cvt16_k<<<144, blk, 0, stream>>>(w_proj2, (half_t*)(ws + H_PRJ), 36864);
    initB1t_k<<<80, blk, 0, stream>>>((half_t*)(ws + H_B1T));
    initB2h_k<<<256, blk, 0, stream>>>((half_t*)(ws + H_B2));
    initB3h_k<<<256, blk, 0, stream>>>((half_t*)(ws + H_B3));
    initB4t_k<<<80, blk, 0, stream>>>((half_t*)(ws + H_B4T));
    fusew_k<<<384, 192, 0, stream>>>(w_kv2, w_proj1, (half_t*)(ws + H_WF));

    // ---- fdfp(x) -> q2 (+ fused q2 norms) ----
    // rowfwd: x (fp32) -> CB0 as fp16 (barrier-free k1big)
    k1big<5, 0, 1, 128><<<dim3(192, 4), blk, 0, stream>>>(
        x, XB, (long)HW, 128L, BIG, 0L,
        (const half_t*)(ws + H_B1T),
        (void*)(ws + CB0), LT_B, (long)FP, LT_ROW, 80, LT_PART, nullptr);
    // colfwd: fp16 CB0 -> fp16 CB1
    k2big<1, 1><<<dim3(240, 4), blk, 0, stream>>>(
        (const half_t*)(ws + H_B2), (const void*)(ws + CB0), (void*)(ws + CB1));
    // FFN: fp16 CB1 -> fp16 CB0
    kff4h<<<dim3(160, 4), 512, 0, stream>>>(
        (const half_t*)(ws + H_W1), (const half_t*)(ws + H_W2),
        (const half_t*)(ws + CB1), (half_t*)(ws + CB0));
    // colinv: fp16 CB0 -> fp32 CB1
    k2big<1, 0><<<dim3(240, 4), blk, 0, stream>>>(
        (const half_t*)(ws + H_B3), (const void*)(ws + CB0), (void*)(ws + CB1));
    // rowinv: fp32 CB1 -> q2 fp32 (+ norms), barrier-free k1big
    k1big<4, 1, 0, 160><<<dim3(192, 4), blk, 0, stream>>>(
        ws + CB1, LT_B, (long)FP, LT_ROW, 80, LT_PART,
        (const half_t*)(ws + H_B4T),
        (void*)(ws + OFF_Q2), XB, (long)HW, 128L, BIG, 0L, ws + SM_INVQ2);

    // ---- stage 1: qkv = dw3(kcv(x)) in 3 chunks (+ fused q1/k1 norms) ----
    for (int ch = 0; ch < 3; ++ch) {
        kcv<4><<<dim3(256, 4), 256, 0, stream>>>(
            (const half_t*)(ws + H_WQKV) + (long)ch * 192 * 192,
            x, XB, ws + OFF_T1, XB);
        dw3_k<<<dim3(192, 4), blk, 0, stream>>>(
            ws + OFF_T1, XB, w_qkv1dw + ch * 192 * 9,
            ws + (long)ch * 192 * HW, (long)576 * HW,
            ch == 2 ? 0 : 192,
            ch == 0 ? ws + SM_INVQ1 : ws + SM_INVK1);
    }
    // stage-1 partials at OFF_T1: qkv [0..37.7M) live, OFF_T1 [37.7M..] free.
    gramf_k<<<dim3(32, GSL), 576, 0, stream>>>(
        ws, (long)576 * HW, ws + (long)192 * HW, (long)576 * HW, ws + OFF_T1);
    softmax_k<<<32, blk, 0, stream>>>(ws + OFF_T1, ws + SM_INVQ1, ws + SM_INVK1, temp, ws + SM_ATT);
    attnapply_k<<<dim3(64, 32), blk, 0, stream>>>(
        ws + SM_ATT, ws + (long)384 * HW, (long)576 * HW, ws + OFF_T1, XB);

    // ---- kv2 = dw3(kcv(out1, Wf)) (+ fused k2 norms) ----
    kcv<8><<<dim3(256, 4), 512, 0, stream>>>(
        (const half_t*)(ws + H_WF), ws + OFF_T1, XB, ws + OFF_KT, (long)384 * HW);
    dw3_k<<<dim3(384, 4), blk, 0, stream>>>(
        ws + OFF_KT, (long)384 * HW, w_kv2dw, ws + OFF_KF, (long)384 * HW,
        192, ws + SM_INVK2);

    // ---- stage 2 attention ----
    // partials at ws[0..1.18M): kv2 pre-dw tmp region, dead after dw3.
    // (NOT OFF_T1 — that aliases kv2 batch 2, the r6-r8 corruption.)
    gramf_k<<<dim3(32, GSL), 576, 0, stream>>>(
        ws + OFF_Q2, XB, ws + OFF_KF, (long)384 * HW, ws + OFF_KT);
    softmax_k<<<32, blk, 0, stream>>>(ws + OFF_KT, ws + SM_INVQ2, ws + SM_INVK2, temp, ws + SM_ATT);
    attnapply_k<<<dim3(64, 32), blk, 0, stream>>>(
        ws + SM_ATT, ws + OFF_KF + (long)192 * HW, (long)384 * HW, ws + OFF_O2, XB);
    kcv<4><<<dim3(256, 4), 256, 0, stream>>>(
        (const half_t*)(ws + H_PRJ), ws + OFF_O2, XB, out, XB);
}

// Round 21
// 564.021 us; speedup vs baseline: 1.0295x; 1.0255x over previous
//
#include <hip/hip_runtime.h>
#include <math.h>

typedef _Float16 half_t;
typedef half_t h8v __attribute__((ext_vector_type(8)));
typedef half_t h4v __attribute__((ext_vector_type(4)));
typedef float f32x4 __attribute__((ext_vector_type(4)));

namespace {
constexpr int DIMC = 192;
constexpr int NB = 4;
constexpr int HH = 128, WW = 128;
constexpr int HW = HH * WW;              // 16384
constexpr int NH = 8, HD = 24;
constexpr int FP = 80;                   // padded kx width (65 valid)
constexpr long LT_PART = 128L * 192 * FP;          // 1,966,080
constexpr long LT_B    = 2 * LT_PART;              // 3,932,160
constexpr long LT_ROW  = 192L * FP;                // 15360
constexpr long XB  = 192L * HW;                    // 3,145,728
constexpr long CB0 = 0;
constexpr long CB1 = 15728640;
constexpr long OFF_T1 = 37748736;        // conv tmp / out1 / stage-1 gram partials
constexpr long OFF_Q2 = 50331648;        // q2
constexpr long OFF_S  = 62914560;        // small region
constexpr long OFF_KT = 0;               // kv2 pre-dw tmp / stage-2 gram partials
constexpr long OFF_KF = 25165824;        // kv2 final  [25.1M..50.3M) — overlaps OFF_T1!
constexpr long OFF_O2 = 0;               // out2 tmp
constexpr int  GSL = 64;                 // gram l-slices (256 l each)
constexpr long SM_INVQ1 = OFF_S;                // 768
constexpr long SM_INVK1 = OFF_S + 768;          // 768
constexpr long SM_INVQ2 = OFF_S + 1536;         // 768
constexpr long SM_INVK2 = OFF_S + 2304;         // 768
constexpr long SM_ATT   = OFF_S + 3072;         // 18,432
constexpr long H0       = OFF_S + 168960;       // fp16 pool (float units)
constexpr long H_WQKV = H0;                     // 110,592 h
constexpr long H_WF   = H0 + 55296;             // 73,728 h
constexpr long H_W1   = H0 + 92160;             // 147,456 h
constexpr long H_W2   = H0 + 165888;            // 147,456 h
constexpr long H_PRJ  = H0 + 239616;            // 36,864 h
constexpr long H_B2   = H0 + 258048;            // 65,536 h
constexpr long H_B3   = H0 + 290816;            // 65,536 h
constexpr long H_B1T  = H0 + 323584;            // 160x128 h
constexpr long H_B4T  = H0 + 333824;            // 128x160 h
constexpr float PI2 = 6.283185307179586476f;
}

// ================= merged init: all fp16 weights/bases in ONE dispatch =======
// ranges (blocks of 256): [0,432) wqkv | [432,1008) w1 | [1008,1584) w2 |
// [1584,1728) prj | [1728,1808) B1t | [1808,2064) B2 | [2064,2320) B3 |
// [2320,2400) B4t | [2400,2688) fusew
__global__ __launch_bounds__(256) void init_all_k(
    const float* __restrict__ w_qkv1, const float* __restrict__ w_fdfp1,
    const float* __restrict__ w_fdfp2, const float* __restrict__ w_proj2,
    const float* __restrict__ w_kv2, const float* __restrict__ w_proj1,
    float* __restrict__ ws) {
    const int b = blockIdx.x, t = threadIdx.x;
    if (b < 432) {
        int i = b * 256 + t;
        if (i < 110592) ((half_t*)(ws + H_WQKV))[i] = (half_t)w_qkv1[i];
    } else if (b < 1008) {
        int i = (b - 432) * 256 + t;
        if (i < 147456) ((half_t*)(ws + H_W1))[i] = (half_t)w_fdfp1[i];
    } else if (b < 1584) {
        int i = (b - 1008) * 256 + t;
        if (i < 147456) ((half_t*)(ws + H_W2))[i] = (half_t)w_fdfp2[i];
    } else if (b < 1728) {
        int i = (b - 1584) * 256 + t;
        if (i < 36864) ((half_t*)(ws + H_PRJ))[i] = (half_t)w_proj2[i];
    } else if (b < 1808) {
        int idx = (b - 1728) * 256 + t;
        if (idx < 160 * 128) {
            int j = idx / 128, k = idx % 128;
            float v = 0.f;
            if (j < 65) v = cosf(PI2 * ((k * j) & 127) / 128.f) * (1.f / 128.f);
            else if (j >= 80 && j < 145) v = -sinf(PI2 * ((k * (j - 80)) & 127) / 128.f) * (1.f / 128.f);
            ((half_t*)(ws + H_B1T))[idx] = (half_t)v;
        }
    } else if (b < 2064) {
        int idx = (b - 1808) * 256 + t;
        int m = idx >> 8, cin = idx & 255;
        int pd = m >> 7, ky = m & 127;
        int ps = cin >> 7, y = cin & 127;
        float c, s; sincosf(PI2 * ((ky * y) & 127) / 128.f, &s, &c);
        float v = (pd == 0) ? (ps == 0 ? c : s) : (ps == 0 ? -s : c);
        ((half_t*)(ws + H_B2))[idx] = (half_t)v;
    } else if (b < 2320) {
        int idx = (b - 2064) * 256 + t;
        int m = idx >> 8, cin = idx & 255;
        int pd = m >> 7, y = m & 127;
        int ps = cin >> 7, ky = cin & 127;
        float c, s; sincosf(PI2 * ((y * ky) & 127) / 128.f, &s, &c);
        float v = (pd == 0) ? (ps == 0 ? c : -s) : (ps == 0 ? s : c);
        ((half_t*)(ws + H_B3))[idx] = (half_t)v;
    } else if (b < 2400) {
        int idx = (b - 2320) * 256 + t;
        if (idx < 128 * 160) {
            int j = idx / 160, k = idx % 160;
            float v = 0.f;
            if (k < 80) {
                if (k == 0) v = 1.f / 128.f;
                else if (k < 64) v = 2.f * cosf(PI2 * ((k * j) & 127) / 128.f) / 128.f;
                else if (k == 64) v = cosf(PI2 * ((64 * j) & 127) / 128.f) / 128.f;
            } else {
                int kx = k - 80;
                if (kx >= 1 && kx < 64) v = -2.f * sinf(PI2 * ((kx * j) & 127) / 128.f) / 128.f;
            }
            ((half_t*)(ws + H_B4T))[idx] = (half_t)v;
        }
    } else {
        int idx = (b - 2400) * 256 + t;    // < 73728 = 384*192
        int o = idx / 192, c = idx - o * 192;
        float acc = 0.f;
        for (int m = 0; m < 192; ++m) acc += w_kv2[o * 192 + m] * w_proj1[m * 192 + c];
        ((half_t*)(ws + H_WF))[idx] = (half_t)acc;
    }
}

// ================= KCV: 1x1 conv, X staged once, W direct from global ========
template<int NW>
__global__ __launch_bounds__(NW * 64) void kcv(
    const half_t* __restrict__ W, const float* __restrict__ X, long xB,
    float* __restrict__ out, long oB) {
    __shared__ __align__(16) half_t S[6 * 64 * 40];     // 30720 B
    const int t = threadIdx.x;
    const long p0 = (long)blockIdx.x * 64;
    const long xb = (long)blockIdx.y * xB;
    const long ob = (long)blockIdx.y * oB;
    const int lane = t & 63, wv = t >> 6;
    const int fr = lane & 15, fg = lane >> 4;
    {
        const int sp = t & 63;
        const int g = t >> 6;
        const float* gp = X + xb + p0 + sp;
        for (int grp = g; grp < 48; grp += NW) {
            int ci0 = grp * 4;
            h4v h;
#pragma unroll
            for (int j = 0; j < 4; ++j) h[j] = (half_t)gp[(long)(ci0 + j) * HW];
            *(h4v*)&S[((ci0 >> 5) * 64 + sp) * 40 + (ci0 & 31)] = h;
        }
    }
    __syncthreads();
    f32x4 acc[3][4];
#pragma unroll
    for (int m = 0; m < 3; ++m)
#pragma unroll
        for (int n = 0; n < 4; ++n) acc[m][n] = {0.f, 0.f, 0.f, 0.f};
    for (int k0 = 0; k0 < 192; k0 += 32) {
        const int s = k0 >> 5;
        h8v a[3], bb[4];
#pragma unroll
        for (int m = 0; m < 3; ++m)
            a[m] = *(const h8v*)(W + (long)(wv * 48 + m * 16 + fr) * 192 + k0 + fg * 8);
#pragma unroll
        for (int n = 0; n < 4; ++n)
            bb[n] = *(const h8v*)&S[(s * 64 + n * 16 + fr) * 40 + fg * 8];
#pragma unroll
        for (int m = 0; m < 3; ++m)
#pragma unroll
            for (int n = 0; n < 4; ++n)
                acc[m][n] = __builtin_amdgcn_mfma_f32_16x16x32_f16(a[m], bb[n], acc[m][n], 0, 0, 0);
    }
#pragma unroll
    for (int m = 0; m < 3; ++m)
#pragma unroll
        for (int i = 0; i < 4; ++i) {
            int o = wv * 48 + m * 16 + fg * 4 + i;
            float* row = out + ob + (long)o * HW + p0;
#pragma unroll
            for (int n = 0; n < 4; ++n) row[n * 16 + fr] = acc[m][n][i];
        }
}

// ================= K2BIG: 256-o column-DFT GEMM, X staged once ===============
template<int IN16, int OUT16>
__global__ __launch_bounds__(256) void k2big(
    const half_t* __restrict__ B16,           // [256 o][256 k] fp16
    const void* __restrict__ Xv, void* __restrict__ outv) {
    __shared__ __align__(16) half_t Xh[8 * 64 * 40];    // 40 KB
    const int t = threadIdx.x;
    const long p0 = (long)blockIdx.x * 64;
    const long xb = (long)blockIdx.y * LT_B;
    const int lane = t & 63, wv = t >> 6;
    const int fr = lane & 15, fg = lane >> 4;
    {
        const int sp = t & 63;
        const int c0 = t >> 6;
#pragma unroll 8
        for (int j = 0; j < 64; ++j) {
            int ci = c0 + j * 4;
            long rb = (ci < 128) ? (long)ci * LT_ROW : (long)(ci - 128) * LT_ROW + LT_PART;
            half_t hv;
            if (IN16) hv = ((const half_t*)Xv)[xb + p0 + sp + rb];
            else      hv = (half_t)((const float*)Xv)[xb + p0 + sp + rb];
            Xh[((ci >> 5) * 64 + sp) * 40 + (ci & 31)] = hv;
        }
    }
    __syncthreads();
    f32x4 acc[4][4];
#pragma unroll
    for (int m = 0; m < 4; ++m)
#pragma unroll
        for (int n = 0; n < 4; ++n) acc[m][n] = {0.f, 0.f, 0.f, 0.f};
    for (int k0 = 0; k0 < 256; k0 += 32) {
        const int s = k0 >> 5;
        h8v a[4], bb[4];
#pragma unroll
        for (int m = 0; m < 4; ++m)
            a[m] = *(const h8v*)(B16 + (long)(wv * 64 + m * 16 + fr) * 256 + k0 + fg * 8);
#pragma unroll
        for (int n = 0; n < 4; ++n)
            bb[n] = *(const h8v*)&Xh[(s * 64 + n * 16 + fr) * 40 + fg * 8];
#pragma unroll
        for (int m = 0; m < 4; ++m)
#pragma unroll
            for (int n = 0; n < 4; ++n)
                acc[m][n] = __builtin_amdgcn_mfma_f32_16x16x32_f16(a[m], bb[n], acc[m][n], 0, 0, 0);
    }
#pragma unroll
    for (int m = 0; m < 4; ++m)
#pragma unroll
        for (int i = 0; i < 4; ++i) {
            int o = wv * 64 + m * 16 + fg * 4 + i;
            long oadr = xb + ((o < 128) ? (long)o * LT_ROW : (long)(o - 128) * LT_ROW + LT_PART);
#pragma unroll
            for (int n = 0; n < 4; ++n) {
                long idx = oadr + p0 + n * 16 + fr;
                if (OUT16) ((half_t*)outv)[idx] = (half_t)acc[m][n][i];
                else       ((float*)outv)[idx]  = acc[m][n][i];
            }
        }
}

// ================= KFF4H: fused W1 -> GELU -> W2, fp16 in/out ================
__global__ __launch_bounds__(512) void kff4h(
    const half_t* __restrict__ W1, const half_t* __restrict__ W2,
    const half_t* __restrict__ X, half_t* __restrict__ out) {
    __shared__ __align__(16) half_t S[12 * 64 * 40];    // 61440 B
    const int t = threadIdx.x;
    const long p0 = (long)blockIdx.x * 64;
    const long xb = (long)blockIdx.y * LT_B;
    const int lane = t & 63, wv = t >> 6;               // 0..7
    const int fr = lane & 15, fg = lane >> 4;
    {
        const int sp = t & 63;
        const int g = t >> 6;                           // 0..7
        long pa; { long p = p0 + sp; long q = p / 80; pa = q * LT_ROW + (p - q * 80); }
        const half_t* gp = X + xb + pa;
#pragma unroll
        for (int ch = 0; ch < 12; ++ch) {
            int ci0 = ch * 32 + g * 4;
            h4v h;
#pragma unroll
            for (int j = 0; j < 4; ++j) {
                int ci = ci0 + j;
                long rb = (ci < 192) ? (long)ci * 80 : (long)(ci - 192) * 80 + LT_PART;
                h[j] = gp[rb];
            }
            *(h4v*)&S[(ch * 64 + sp) * 40 + g * 4] = h;
        }
    }
    __syncthreads();
    f32x4 acc[3][4];
#pragma unroll
    for (int m = 0; m < 3; ++m)
#pragma unroll
        for (int n = 0; n < 4; ++n) acc[m][n] = {0.f, 0.f, 0.f, 0.f};
    for (int k0 = 0; k0 < 384; k0 += 32) {
        const int s = k0 >> 5;
        h8v a[3], bb[4];
#pragma unroll
        for (int m = 0; m < 3; ++m)
            a[m] = *(const h8v*)(W1 + (long)(wv * 48 + m * 16 + fr) * 384 + k0 + fg * 8);
#pragma unroll
        for (int n = 0; n < 4; ++n)
            bb[n] = *(const h8v*)&S[(s * 64 + n * 16 + fr) * 40 + fg * 8];
#pragma unroll
        for (int m = 0; m < 3; ++m)
#pragma unroll
            for (int n = 0; n < 4; ++n)
                acc[m][n] = __builtin_amdgcn_mfma_f32_16x16x32_f16(a[m], bb[n], acc[m][n], 0, 0, 0);
    }
    __syncthreads();
#pragma unroll
    for (int m = 0; m < 3; ++m)
#pragma unroll
        for (int n = 0; n < 4; ++n) {
            int o4 = wv * 48 + m * 16 + fg * 4;
            int p = n * 16 + fr;
            h4v h;
#pragma unroll
            for (int i = 0; i < 4; ++i) {
                float v = acc[m][n][i];
                v = 0.5f * v * (1.f + erff(v * 0.70710678118654752f));
                h[i] = (half_t)v;
            }
            *(h4v*)&S[((o4 >> 5) * 64 + p) * 40 + (o4 & 31)] = h;
        }
#pragma unroll
    for (int m = 0; m < 3; ++m)
#pragma unroll
        for (int n = 0; n < 4; ++n) acc[m][n] = {0.f, 0.f, 0.f, 0.f};
    __syncthreads();
    for (int k0 = 0; k0 < 384; k0 += 32) {
        const int s = k0 >> 5;
        h8v a[3], bb[4];
#pragma unroll
        for (int m = 0; m < 3; ++m)
            a[m] = *(const h8v*)(W2 + (long)(wv * 48 + m * 16 + fr) * 384 + k0 + fg * 8);
#pragma unroll
        for (int n = 0; n < 4; ++n)
            bb[n] = *(const h8v*)&S[(s * 64 + n * 16 + fr) * 40 + fg * 8];
#pragma unroll
        for (int m = 0; m < 3; ++m)
#pragma unroll
            for (int n = 0; n < 4; ++n)
                acc[m][n] = __builtin_amdgcn_mfma_f32_16x16x32_f16(a[m], bb[n], acc[m][n], 0, 0, 0);
    }
    long pe[4];
#pragma unroll
    for (int n = 0; n < 4; ++n) {
        long p = p0 + n * 16 + fr;
        long q = p / 80; pe[n] = q * LT_ROW + (p - q * 80);
    }
#pragma unroll
    for (int m = 0; m < 3; ++m)
#pragma unroll
        for (int i = 0; i < 4; ++i) {
            int o = wv * 48 + m * 16 + fg * 4 + i;
            long oadr = xb + ((o < 192) ? (long)o * 80 : (long)(o - 192) * 80 + LT_PART);
#pragma unroll
            for (int n = 0; n < 4; ++n) out[oadr + pe[n]] = (half_t)acc[m][n][i];
        }
}

// ================= K1BIG: row-DFT GEMM, zero LDS, zero in-loop barriers ======
template<int NF, int NORM, int OUT16, int K>
__global__ __launch_bounds__(256) void k1big(
    const float* __restrict__ A, long aBatch, long aC, long aRow, int aSplit, long aHiOff,
    const half_t* __restrict__ Bt,
    void* __restrict__ outv, long oBatch, long oC, long oRow, int oSplit, long oHiOff,
    float* __restrict__ inv) {
    const int t = threadIdx.x;
    const long ab = (long)blockIdx.y * aBatch + (long)blockIdx.x * aC;
    const long ob = (long)blockIdx.y * oBatch + (long)blockIdx.x * oC;
    const int lane = t & 63, wv = t >> 6;
    const int fr = lane & 15, fg = lane >> 4;
    constexpr int NFR = NF * 2;
    f32x4 acc[2][NFR];
#pragma unroll
    for (int m = 0; m < 2; ++m)
#pragma unroll
        for (int n = 0; n < NFR; ++n) acc[m][n] = {0.f, 0.f, 0.f, 0.f};
    for (int k0 = 0; k0 < K; k0 += 32) {
        int kk = k0 + fg * 8;
        long ka = (kk < aSplit) ? (long)kk : (long)(kk - aSplit) + aHiOff;
        h8v a[2];
#pragma unroll
        for (int m = 0; m < 2; ++m) {
            const float* g = A + ab + (long)(wv * 32 + m * 16 + fr) * aRow + ka;
            float4 v0 = *(const float4*)g;
            float4 v1 = *(const float4*)(g + 4);
            a[m][0] = (half_t)v0.x; a[m][1] = (half_t)v0.y;
            a[m][2] = (half_t)v0.z; a[m][3] = (half_t)v0.w;
            a[m][4] = (half_t)v1.x; a[m][5] = (half_t)v1.y;
            a[m][6] = (half_t)v1.z; a[m][7] = (half_t)v1.w;
        }
        h8v bb[NFR];
#pragma unroll
        for (int n = 0; n < NFR; ++n)
            bb[n] = *(const h8v*)(Bt + (long)(n * 16 + fr) * K + kk);
#pragma unroll
        for (int m = 0; m < 2; ++m)
#pragma unroll
            for (int n = 0; n < NFR; ++n)
                acc[m][n] = __builtin_amdgcn_mfma_f32_16x16x32_f16(a[m], bb[n], acc[m][n], 0, 0, 0);
    }
#pragma unroll
    for (int m = 0; m < 2; ++m)
#pragma unroll
        for (int i = 0; i < 4; ++i) {
            int r = wv * 32 + m * 16 + fg * 4 + i;
            long rbase = ob + (long)r * oRow;
#pragma unroll
            for (int n = 0; n < NFR; ++n) {
                int j = n * 16 + fr;
                long jm = (j < oSplit) ? (long)j : (long)(j - oSplit) + oHiOff;
                if (OUT16) ((half_t*)outv)[rbase + jm] = (half_t)acc[m][n][i];
                else       ((float*)outv)[rbase + jm]  = acc[m][n][i];
            }
        }
    if (NORM) {
        float ss = 0.f;
#pragma unroll
        for (int m = 0; m < 2; ++m)
#pragma unroll
            for (int n = 0; n < NFR; ++n)
#pragma unroll
                for (int i = 0; i < 4; ++i) ss += acc[m][n][i] * acc[m][n][i];
        __shared__ float red[256];
        red[t] = ss;
        __syncthreads();
        for (int st = 128; st > 0; st >>= 1) {
            if (t < st) red[t] += red[t + st];
            __syncthreads();
        }
        if (t == 0) inv[(long)blockIdx.y * 192 + blockIdx.x] = 1.f / fmaxf(sqrtf(red[0]), 1e-12f);
    }
}

// ---------- depthwise 3x3, pad 1: one block per (channel, batch) plane ----------
__global__ __launch_bounds__(256) void dw3_k(
    const float* __restrict__ in, long inBatch,
    const float* __restrict__ w9,
    float* __restrict__ out, long outBatch,
    int normCnt, float* __restrict__ inv) {
    const int c = blockIdx.x, b = blockIdx.y;
    const int t = threadIdx.x;
    const float* ip = in + (long)b * inBatch + (long)c * HW;
    float* op = out + (long)b * outBatch + (long)c * HW;
    const float* wp = w9 + c * 9;
    const float w0 = wp[0], w1 = wp[1], w2 = wp[2];
    const float w3 = wp[3], w4 = wp[4], w5 = wp[5];
    const float w6 = wp[6], w7 = wp[7], w8 = wp[8];
    const int tx = t & 31;
    const int x0 = tx * 4;
    const int y0 = (t >> 5) * 16;
    const bool lx = (tx > 0), rx = (tx < 31);
    float Ar[6], Br[6], Cr[6];
#define LOADROW(Y, R) do { \
        const float* _p = ip + (Y) * 128 + x0; \
        float4 _v = *(const float4*)_p; \
        R[1] = _v.x; R[2] = _v.y; R[3] = _v.z; R[4] = _v.w; \
        R[0] = lx ? _p[-1] : 0.f; \
        R[5] = rx ? _p[4] : 0.f; } while (0)
    if (y0 == 0) { Ar[0]=Ar[1]=Ar[2]=Ar[3]=Ar[4]=Ar[5]=0.f; }
    else LOADROW(y0 - 1, Ar);
    LOADROW(y0, Br);
    float ss = 0.f;
#pragma unroll
    for (int i = 0; i < 16; ++i) {
        int y = y0 + i;
        if (y + 1 < 128) { LOADROW(y + 1, Cr); }
        else { Cr[0]=Cr[1]=Cr[2]=Cr[3]=Cr[4]=Cr[5]=0.f; }
        float o0 = Ar[0]*w0 + Ar[1]*w1 + Ar[2]*w2
                 + Br[0]*w3 + Br[1]*w4 + Br[2]*w5
                 + Cr[0]*w6 + Cr[1]*w7 + Cr[2]*w8;
        float o1 = Ar[1]*w0 + Ar[2]*w1 + Ar[3]*w2
                 + Br[1]*w3 + Br[2]*w4 + Br[3]*w5
                 + Cr[1]*w6 + Cr[2]*w7 + Cr[3]*w8;
        float o2 = Ar[2]*w0 + Ar[3]*w1 + Ar[4]*w2
                 + Br[2]*w3 + Br[3]*w4 + Br[4]*w5
                 + Cr[2]*w6 + Cr[3]*w7 + Cr[4]*w8;
        float o3 = Ar[3]*w0 + Ar[4]*w1 + Ar[5]*w2
                 + Br[3]*w3 + Br[4]*w4 + Br[5]*w5
                 + Cr[3]*w6 + Cr[4]*w7 + Cr[5]*w8;
        *(float4*)(op + y * 128 + x0) = make_float4(o0, o1, o2, o3);
        ss += o0*o0 + o1*o1 + o2*o2 + o3*o3;
#pragma unroll
        for (int j = 0; j < 6; ++j) { Ar[j] = Br[j]; Br[j] = Cr[j]; }
    }
#undef LOADROW
    if (normCnt > 0 && c < normCnt) {
        __shared__ float red[256];
        red[t] = ss;
        __syncthreads();
        for (int st = 128; st > 0; st >>= 1) {
            if (t < st) red[t] += red[t + st];
            __syncthreads();
        }
        if (t == 0) inv[(long)b * 192 + c] = 1.f / fmaxf(sqrtf(red[0]), 1e-12f);
    }
}

// ================= fp32 Gram, slice-parallel =================
__global__ __launch_bounds__(576) void gramf_k(
    const float* __restrict__ q, long qB,
    const float* __restrict__ k, long kB,
    float* __restrict__ gp) {
    __shared__ float qs[HD][260];
    __shared__ float ks[HD][260];
    const int bn = blockIdx.x, ls = blockIdx.y;
    const int b = bn >> 3, n = bn & 7;
    const int t = threadIdx.x;
    const int l0 = ls * 256;
    const float* qp = q + (long)b * qB + (long)(n * HD) * HW + l0;
    const float* kp = k + (long)b * kB + (long)(n * HD) * HW + l0;
    for (int idx = t; idx < HD * 64; idx += 576) {
        int row = idx >> 6, c4 = (idx & 63) * 4;
        *(float4*)&qs[row][c4] = *(const float4*)(qp + (long)row * HW + c4);
        *(float4*)&ks[row][c4] = *(const float4*)(kp + (long)row * HW + c4);
    }
    __syncthreads();
    const int d = t / 24, e = t - d * 24;
    float acc = 0.f;
#pragma unroll 8
    for (int j = 0; j < 256; j += 4) {
        float4 a = *(const float4*)&qs[d][j];
        float4 bb = *(const float4*)&ks[e][j];
        acc += a.x * bb.x + a.y * bb.y + a.z * bb.z + a.w * bb.w;
    }
    gp[((long)bn * 576 + t) * GSL + ls] = acc;
}

// ---------- slice-sum + normalize + temperature + softmax ----------
__global__ __launch_bounds__(256) void softmax_k(
    const float* __restrict__ gp, const float* __restrict__ invq,
    const float* __restrict__ invk, const float* __restrict__ temp,
    float* __restrict__ attn) {
    int bn = blockIdx.x;
    int b = bn >> 3, n = bn & 7;
    int t = threadIdx.x;
    __shared__ float sums[576];
    for (int idx = t; idx < 576; idx += 256) {
        const float* g = gp + ((long)bn * 576 + idx) * GSL;
        float s = 0.f;
        for (int i = 0; i < GSL; i += 4) {
            float4 v = *(const float4*)(g + i);
            s += v.x + v.y + v.z + v.w;
        }
        sums[idx] = s;
    }
    __syncthreads();
    int d = t;
    if (d >= HD) return;
    float tt = temp[n];
    float iq = invq[b * 192 + n * HD + d];
    float row[HD];
#pragma unroll
    for (int e = 0; e < HD; ++e)
        row[e] = sums[d * HD + e] * iq * invk[b * 192 + n * HD + e] * tt;
    float m = row[0];
#pragma unroll
    for (int e = 1; e < HD; ++e) m = fmaxf(m, row[e]);
    float ssum = 0.f;
#pragma unroll
    for (int e = 0; e < HD; ++e) { row[e] = expf(row[e] - m); ssum += row[e]; }
    float is = 1.f / ssum;
#pragma unroll
    for (int e = 0; e < HD; ++e) attn[(long)bn * 576 + d * HD + e] = row[e] * is;
}

// ---------- out[d,p] = sum_e attn[d,e] * v[e,p] ----------
__global__ void attnapply_k(const float* __restrict__ attn, const float* __restrict__ v,
                            long vB, float* __restrict__ out, long outB) {
    int p = blockIdx.x * 256 + threadIdx.x;
    int bn = blockIdx.y;
    int b = bn >> 3, n = bn & 7;
    __shared__ float a[576];
    for (int i = threadIdx.x; i < 576; i += 256) a[i] = attn[(long)bn * 576 + i];
    __syncthreads();
    const float* vp = v + (long)b * vB + (long)(n * HD) * HW + p;
    float acc[HD];
#pragma unroll
    for (int d = 0; d < HD; ++d) acc[d] = 0.f;
    for (int e = 0; e < HD; ++e) {
        float vv = vp[(long)e * HW];
#pragma unroll
        for (int d = 0; d < HD; ++d) acc[d] += a[d * HD + e] * vv;
    }
    float* op = out + (long)b * outB + (long)(n * HD) * HW + p;
#pragma unroll
    for (int d = 0; d < HD; ++d) op[(long)d * HW] = acc[d];
}

extern "C" void kernel_launch(void* const* d_in, const int* in_sizes, int n_in,
                              void* d_out, int out_size, void* d_ws, size_t ws_size,
                              hipStream_t stream) {
    const float* x        = (const float*)d_in[0];
    const float* w_qkv1   = (const float*)d_in[1];
    const float* w_qkv1dw = (const float*)d_in[2];
    const float* w_proj1  = (const float*)d_in[3];
    const float* w_fdfp1  = (const float*)d_in[4];
    const float* w_fdfp2  = (const float*)d_in[5];
    const float* w_kv2    = (const float*)d_in[6];
    const float* w_kv2dw  = (const float*)d_in[7];
    const float* w_proj2  = (const float*)d_in[8];
    const float* temp     = (const float*)d_in[9];
    float* out = (float*)d_out;
    float* ws  = (float*)d_ws;
    dim3 blk(256);
    const int BIG = 1 << 20;

    // ---- init: all fp16 weights/bases in one dispatch ----
    init_all_k<<<2688, blk, 0, stream>>>(
        w_qkv1, w_fdfp1, w_fdfp2, w_proj2, w_kv2, w_proj1, ws);

    // ---- fdfp(x) -> q2 (+ fused q2 norms) ----
    // rowfwd: x (fp32) -> CB0 as fp16 (barrier-free k1big)
    k1big<5, 0, 1, 128><<<dim3(192, 4), blk, 0, stream>>>(
        x, XB, (long)HW, 128L, BIG, 0L,
        (const half_t*)(ws + H_B1T),
        (void*)(ws + CB0), LT_B, (long)FP, LT_ROW, 80, LT_PART, nullptr);
    // colfwd: fp16 CB0 -> fp16 CB1
    k2big<1, 1><<<dim3(240, 4), blk, 0, stream>>>(
        (const half_t*)(ws + H_B2), (const void*)(ws + CB0), (void*)(ws + CB1));
    // FFN: fp16 CB1 -> fp16 CB0
    kff4h<<<dim3(160, 4), 512, 0, stream>>>(
        (const half_t*)(ws + H_W1), (const half_t*)(ws + H_W2),
        (const half_t*)(ws + CB1), (half_t*)(ws + CB0));
    // colinv: fp16 CB0 -> fp32 CB1
    k2big<1, 0><<<dim3(240, 4), blk, 0, stream>>>(
        (const half_t*)(ws + H_B3), (const void*)(ws + CB0), (void*)(ws + CB1));
    // rowinv: fp32 CB1 -> q2 fp32 (+ norms), barrier-free k1big
    k1big<4, 1, 0, 160><<<dim3(192, 4), blk, 0, stream>>>(
        ws + CB1, LT_B, (long)FP, LT_ROW, 80, LT_PART,
        (const half_t*)(ws + H_B4T),
        (void*)(ws + OFF_Q2), XB, (long)HW, 128L, BIG, 0L, ws + SM_INVQ2);

    // ---- stage 1: qkv = dw3(kcv(x)) in 3 chunks (+ fused q1/k1 norms) ----
    for (int ch = 0; ch < 3; ++ch) {
        kcv<4><<<dim3(256, 4), 256, 0, stream>>>(
            (const half_t*)(ws + H_WQKV) + (long)ch * 192 * 192,
            x, XB, ws + OFF_T1, XB);
        dw3_k<<<dim3(192, 4), blk, 0, stream>>>(
            ws + OFF_T1, XB, w_qkv1dw + ch * 192 * 9,
            ws + (long)ch * 192 * HW, (long)576 * HW,
            ch == 2 ? 0 : 192,
            ch == 0 ? ws + SM_INVQ1 : ws + SM_INVK1);
    }
    // stage-1 partials at OFF_T1: qkv [0..37.7M) live, OFF_T1 [37.7M..] free.
    gramf_k<<<dim3(32, GSL), 576, 0, stream>>>(
        ws, (long)576 * HW, ws + (long)192 * HW, (long)576 * HW, ws + OFF_T1);
    softmax_k<<<32, blk, 0, stream>>>(ws + OFF_T1, ws + SM_INVQ1, ws + SM_INVK1, temp, ws + SM_ATT);
    attnapply_k<<<dim3(64, 32), blk, 0, stream>>>(
        ws + SM_ATT, ws + (long)384 * HW, (long)576 * HW, ws + OFF_T1, XB);

    // ---- kv2 = dw3(kcv(out1, Wf)) (+ fused k2 norms) ----
    kcv<8><<<dim3(256, 4), 512, 0, stream>>>(
        (const half_t*)(ws + H_WF), ws + OFF_T1, XB, ws + OFF_KT, (long)384 * HW);
    dw3_k<<<dim3(384, 4), blk, 0, stream>>>(
        ws + OFF_KT, (long)384 * HW, w_kv2dw, ws + OFF_KF, (long)384 * HW,
        192, ws + SM_INVK2);

    // ---- stage 2 attention ----
    // partials at ws[0..1.18M): kv2 pre-dw tmp region, dead after dw3.
    // (NOT OFF_T1 — that aliases kv2 batch 2, the r6-r8 corruption.)
    gramf_k<<<dim3(32, GSL), 576, 0, stream>>>(
        ws + OFF_Q2, XB, ws + OFF_KF, (long)384 * HW, ws + OFF_KT);
    softmax_k<<<32, blk, 0, stream>>>(ws + OFF_KT, ws + SM_INVQ2, ws + SM_INVK2, temp, ws + SM_ATT);
    attnapply_k<<<dim3(64, 32), blk, 0, stream>>>(
        ws + SM_ATT, ws + OFF_KF + (long)192 * HW, (long)384 * HW, ws + OFF_O2, XB);
    kcv<4><<<dim3(256, 4), 256, 0, stream>>>(
        (const half_t*)(ws + H_PRJ), ws + OFF_O2, XB, out, XB);
}

// Round 22
// 563.557 us; speedup vs baseline: 1.0304x; 1.0008x over previous
//
#include <hip/hip_runtime.h>
#include <math.h>

typedef _Float16 half_t;
typedef half_t h8v __attribute__((ext_vector_type(8)));
typedef half_t h4v __attribute__((ext_vector_type(4)));
typedef float f32x4 __attribute__((ext_vector_type(4)));

namespace {
constexpr int DIMC = 192;
constexpr int NB = 4;
constexpr int HH = 128, WW = 128;
constexpr int HW = HH * WW;              // 16384
constexpr int NH = 8, HD = 24;
constexpr int FP = 80;                   // padded kx width (65 valid)
constexpr long LT_PART = 128L * 192 * FP;          // 1,966,080
constexpr long LT_B    = 2 * LT_PART;              // 3,932,160
constexpr long LT_ROW  = 192L * FP;                // 15360
constexpr long XB  = 192L * HW;                    // 3,145,728
constexpr long CB0 = 0;
constexpr long CB1 = 15728640;
constexpr long OFF_T1 = 37748736;        // conv tmp / out1 / stage-1 gram partials
constexpr long OFF_Q2 = 50331648;        // q2
constexpr long OFF_S  = 62914560;        // small region
constexpr long OFF_KT = 0;               // kv2 pre-dw tmp / stage-2 gram partials
constexpr long OFF_KF = 25165824;        // kv2 final  [25.1M..50.3M) — overlaps OFF_T1!
constexpr long OFF_O2 = 0;               // out2 tmp
constexpr int  GSL = 64;                 // gram l-slices (256 l each)
constexpr long SM_INVQ1 = OFF_S;                // 768
constexpr long SM_INVK1 = OFF_S + 768;          // 768
constexpr long SM_INVQ2 = OFF_S + 1536;         // 768
constexpr long SM_INVK2 = OFF_S + 2304;         // 768
constexpr long SM_ATT   = OFF_S + 3072;         // 18,432
constexpr long H0       = OFF_S + 168960;       // fp16 pool (float units)
constexpr long H_WQKV = H0;                     // 110,592 h
constexpr long H_WF   = H0 + 55296;             // 73,728 h
constexpr long H_W1   = H0 + 92160;             // 147,456 h
constexpr long H_W2   = H0 + 165888;            // 147,456 h
constexpr long H_PRJ  = H0 + 239616;            // 36,864 h
constexpr long H_B2   = H0 + 258048;            // 65,536 h
constexpr long H_B3   = H0 + 290816;            // 65,536 h
constexpr long H_B1T  = H0 + 323584;            // 160x128 h
constexpr long H_B4T  = H0 + 333824;            // 128x160 h
constexpr float PI2 = 6.283185307179586476f;
}

// ================= merged init: all fp16 weights/bases in ONE dispatch =======
__global__ __launch_bounds__(256) void init_all_k(
    const float* __restrict__ w_qkv1, const float* __restrict__ w_fdfp1,
    const float* __restrict__ w_fdfp2, const float* __restrict__ w_proj2,
    const float* __restrict__ w_kv2, const float* __restrict__ w_proj1,
    float* __restrict__ ws) {
    const int b = blockIdx.x, t = threadIdx.x;
    if (b < 432) {
        int i = b * 256 + t;
        if (i < 110592) ((half_t*)(ws + H_WQKV))[i] = (half_t)w_qkv1[i];
    } else if (b < 1008) {
        int i = (b - 432) * 256 + t;
        if (i < 147456) ((half_t*)(ws + H_W1))[i] = (half_t)w_fdfp1[i];
    } else if (b < 1584) {
        int i = (b - 1008) * 256 + t;
        if (i < 147456) ((half_t*)(ws + H_W2))[i] = (half_t)w_fdfp2[i];
    } else if (b < 1728) {
        int i = (b - 1584) * 256 + t;
        if (i < 36864) ((half_t*)(ws + H_PRJ))[i] = (half_t)w_proj2[i];
    } else if (b < 1808) {
        int idx = (b - 1728) * 256 + t;
        if (idx < 160 * 128) {
            int j = idx / 128, k = idx % 128;
            float v = 0.f;
            if (j < 65) v = cosf(PI2 * ((k * j) & 127) / 128.f) * (1.f / 128.f);
            else if (j >= 80 && j < 145) v = -sinf(PI2 * ((k * (j - 80)) & 127) / 128.f) * (1.f / 128.f);
            ((half_t*)(ws + H_B1T))[idx] = (half_t)v;
        }
    } else if (b < 2064) {
        int idx = (b - 1808) * 256 + t;
        int m = idx >> 8, cin = idx & 255;
        int pd = m >> 7, ky = m & 127;
        int ps = cin >> 7, y = cin & 127;
        float c, s; sincosf(PI2 * ((ky * y) & 127) / 128.f, &s, &c);
        float v = (pd == 0) ? (ps == 0 ? c : s) : (ps == 0 ? -s : c);
        ((half_t*)(ws + H_B2))[idx] = (half_t)v;
    } else if (b < 2320) {
        int idx = (b - 2064) * 256 + t;
        int m = idx >> 8, cin = idx & 255;
        int pd = m >> 7, y = m & 127;
        int ps = cin >> 7, ky = cin & 127;
        float c, s; sincosf(PI2 * ((y * ky) & 127) / 128.f, &s, &c);
        float v = (pd == 0) ? (ps == 0 ? c : -s) : (ps == 0 ? s : c);
        ((half_t*)(ws + H_B3))[idx] = (half_t)v;
    } else if (b < 2400) {
        int idx = (b - 2320) * 256 + t;
        if (idx < 128 * 160) {
            int j = idx / 160, k = idx % 160;
            float v = 0.f;
            if (k < 80) {
                if (k == 0) v = 1.f / 128.f;
                else if (k < 64) v = 2.f * cosf(PI2 * ((k * j) & 127) / 128.f) / 128.f;
                else if (k == 64) v = cosf(PI2 * ((64 * j) & 127) / 128.f) / 128.f;
            } else {
                int kx = k - 80;
                if (kx >= 1 && kx < 64) v = -2.f * sinf(PI2 * ((kx * j) & 127) / 128.f) / 128.f;
            }
            ((half_t*)(ws + H_B4T))[idx] = (half_t)v;
        }
    } else {
        int idx = (b - 2400) * 256 + t;    // < 73728 = 384*192
        int o = idx / 192, c = idx - o * 192;
        float acc = 0.f;
        for (int m = 0; m < 192; ++m) acc += w_kv2[o * 192 + m] * w_proj1[m * 192 + c];
        ((half_t*)(ws + H_WF))[idx] = (half_t)acc;
    }
}

// ================= KCV: 1x1 conv, X staged once, W direct from global ========
template<int NW>
__global__ __launch_bounds__(NW * 64) void kcv(
    const half_t* __restrict__ W, const float* __restrict__ X, long xB,
    float* __restrict__ out, long oB) {
    __shared__ __align__(16) half_t S[6 * 64 * 40];     // 30720 B
    const int t = threadIdx.x;
    const long p0 = (long)blockIdx.x * 64;
    const long xb = (long)blockIdx.y * xB;
    const long ob = (long)blockIdx.y * oB;
    const int lane = t & 63, wv = t >> 6;
    const int fr = lane & 15, fg = lane >> 4;
    {
        const int sp = t & 63;
        const int g = t >> 6;
        const float* gp = X + xb + p0 + sp;
        for (int grp = g; grp < 48; grp += NW) {
            int ci0 = grp * 4;
            h4v h;
#pragma unroll
            for (int j = 0; j < 4; ++j) h[j] = (half_t)gp[(long)(ci0 + j) * HW];
            *(h4v*)&S[((ci0 >> 5) * 64 + sp) * 40 + (ci0 & 31)] = h;
        }
    }
    __syncthreads();
    f32x4 acc[3][4];
#pragma unroll
    for (int m = 0; m < 3; ++m)
#pragma unroll
        for (int n = 0; n < 4; ++n) acc[m][n] = {0.f, 0.f, 0.f, 0.f};
    for (int k0 = 0; k0 < 192; k0 += 32) {
        const int s = k0 >> 5;
        h8v a[3], bb[4];
#pragma unroll
        for (int m = 0; m < 3; ++m)
            a[m] = *(const h8v*)(W + (long)(wv * 48 + m * 16 + fr) * 192 + k0 + fg * 8);
#pragma unroll
        for (int n = 0; n < 4; ++n)
            bb[n] = *(const h8v*)&S[(s * 64 + n * 16 + fr) * 40 + fg * 8];
#pragma unroll
        for (int m = 0; m < 3; ++m)
#pragma unroll
            for (int n = 0; n < 4; ++n)
                acc[m][n] = __builtin_amdgcn_mfma_f32_16x16x32_f16(a[m], bb[n], acc[m][n], 0, 0, 0);
    }
#pragma unroll
    for (int m = 0; m < 3; ++m)
#pragma unroll
        for (int i = 0; i < 4; ++i) {
            int o = wv * 48 + m * 16 + fg * 4 + i;
            float* row = out + ob + (long)o * HW + p0;
#pragma unroll
            for (int n = 0; n < 4; ++n) row[n * 16 + fr] = acc[m][n][i];
        }
}

// ================= K2BIG: 256-o column-DFT GEMM, X staged once ===============
template<int IN16, int OUT16>
__global__ __launch_bounds__(256) void k2big(
    const half_t* __restrict__ B16,           // [256 o][256 k] fp16
    const void* __restrict__ Xv, void* __restrict__ outv) {
    __shared__ __align__(16) half_t Xh[8 * 64 * 40];    // 40 KB
    const int t = threadIdx.x;
    const long p0 = (long)blockIdx.x * 64;
    const long xb = (long)blockIdx.y * LT_B;
    const int lane = t & 63, wv = t >> 6;
    const int fr = lane & 15, fg = lane >> 4;
    {
        const int sp = t & 63;
        const int c0 = t >> 6;
#pragma unroll 8
        for (int j = 0; j < 64; ++j) {
            int ci = c0 + j * 4;
            long rb = (ci < 128) ? (long)ci * LT_ROW : (long)(ci - 128) * LT_ROW + LT_PART;
            half_t hv;
            if (IN16) hv = ((const half_t*)Xv)[xb + p0 + sp + rb];
            else      hv = (half_t)((const float*)Xv)[xb + p0 + sp + rb];
            Xh[((ci >> 5) * 64 + sp) * 40 + (ci & 31)] = hv;
        }
    }
    __syncthreads();
    f32x4 acc[4][4];
#pragma unroll
    for (int m = 0; m < 4; ++m)
#pragma unroll
        for (int n = 0; n < 4; ++n) acc[m][n] = {0.f, 0.f, 0.f, 0.f};
    for (int k0 = 0; k0 < 256; k0 += 32) {
        const int s = k0 >> 5;
        h8v a[4], bb[4];
#pragma unroll
        for (int m = 0; m < 4; ++m)
            a[m] = *(const h8v*)(B16 + (long)(wv * 64 + m * 16 + fr) * 256 + k0 + fg * 8);
#pragma unroll
        for (int n = 0; n < 4; ++n)
            bb[n] = *(const h8v*)&Xh[(s * 64 + n * 16 + fr) * 40 + fg * 8];
#pragma unroll
        for (int m = 0; m < 4; ++m)
#pragma unroll
            for (int n = 0; n < 4; ++n)
                acc[m][n] = __builtin_amdgcn_mfma_f32_16x16x32_f16(a[m], bb[n], acc[m][n], 0, 0, 0);
    }
#pragma unroll
    for (int m = 0; m < 4; ++m)
#pragma unroll
        for (int i = 0; i < 4; ++i) {
            int o = wv * 64 + m * 16 + fg * 4 + i;
            long oadr = xb + ((o < 128) ? (long)o * LT_ROW : (long)(o - 128) * LT_ROW + LT_PART);
#pragma unroll
            for (int n = 0; n < 4; ++n) {
                long idx = oadr + p0 + n * 16 + fr;
                if (OUT16) ((half_t*)outv)[idx] = (half_t)acc[m][n][i];
                else       ((float*)outv)[idx]  = acc[m][n][i];
            }
        }
}

// ================= KFF4H: fused W1 -> GELU -> W2, fp16 in/out ================
// LDS stride 32 (no pad): 49,152 B -> 3 blocks/CU (single wave-round at grid 640).
// Accepts ~8-way bank conflicts on b-frag reads — A/B vs stride-40 occupancy.
__global__ __launch_bounds__(512) void kff4h(
    const half_t* __restrict__ W1, const half_t* __restrict__ W2,
    const half_t* __restrict__ X, half_t* __restrict__ out) {
    __shared__ __align__(16) half_t S[12 * 64 * 32];    // 49152 B
    const int t = threadIdx.x;
    const long p0 = (long)blockIdx.x * 64;
    const long xb = (long)blockIdx.y * LT_B;
    const int lane = t & 63, wv = t >> 6;               // 0..7
    const int fr = lane & 15, fg = lane >> 4;
    {
        const int sp = t & 63;
        const int g = t >> 6;                           // 0..7
        long pa; { long p = p0 + sp; long q = p / 80; pa = q * LT_ROW + (p - q * 80); }
        const half_t* gp = X + xb + pa;
#pragma unroll
        for (int ch = 0; ch < 12; ++ch) {
            int ci0 = ch * 32 + g * 4;
            h4v h;
#pragma unroll
            for (int j = 0; j < 4; ++j) {
                int ci = ci0 + j;
                long rb = (ci < 192) ? (long)ci * 80 : (long)(ci - 192) * 80 + LT_PART;
                h[j] = gp[rb];
            }
            *(h4v*)&S[(ch * 64 + sp) * 32 + g * 4] = h;
        }
    }
    __syncthreads();
    f32x4 acc[3][4];
#pragma unroll
    for (int m = 0; m < 3; ++m)
#pragma unroll
        for (int n = 0; n < 4; ++n) acc[m][n] = {0.f, 0.f, 0.f, 0.f};
    for (int k0 = 0; k0 < 384; k0 += 32) {
        const int s = k0 >> 5;
        h8v a[3], bb[4];
#pragma unroll
        for (int m = 0; m < 3; ++m)
            a[m] = *(const h8v*)(W1 + (long)(wv * 48 + m * 16 + fr) * 384 + k0 + fg * 8);
#pragma unroll
        for (int n = 0; n < 4; ++n)
            bb[n] = *(const h8v*)&S[(s * 64 + n * 16 + fr) * 32 + fg * 8];
#pragma unroll
        for (int m = 0; m < 3; ++m)
#pragma unroll
            for (int n = 0; n < 4; ++n)
                acc[m][n] = __builtin_amdgcn_mfma_f32_16x16x32_f16(a[m], bb[n], acc[m][n], 0, 0, 0);
    }
    __syncthreads();
#pragma unroll
    for (int m = 0; m < 3; ++m)
#pragma unroll
        for (int n = 0; n < 4; ++n) {
            int o4 = wv * 48 + m * 16 + fg * 4;
            int p = n * 16 + fr;
            h4v h;
#pragma unroll
            for (int i = 0; i < 4; ++i) {
                float v = acc[m][n][i];
                v = 0.5f * v * (1.f + erff(v * 0.70710678118654752f));
                h[i] = (half_t)v;
            }
            *(h4v*)&S[((o4 >> 5) * 64 + p) * 32 + (o4 & 31)] = h;
        }
#pragma unroll
    for (int m = 0; m < 3; ++m)
#pragma unroll
        for (int n = 0; n < 4; ++n) acc[m][n] = {0.f, 0.f, 0.f, 0.f};
    __syncthreads();
    for (int k0 = 0; k0 < 384; k0 += 32) {
        const int s = k0 >> 5;
        h8v a[3], bb[4];
#pragma unroll
        for (int m = 0; m < 3; ++m)
            a[m] = *(const h8v*)(W2 + (long)(wv * 48 + m * 16 + fr) * 384 + k0 + fg * 8);
#pragma unroll
        for (int n = 0; n < 4; ++n)
            bb[n] = *(const h8v*)&S[(s * 64 + n * 16 + fr) * 32 + fg * 8];
#pragma unroll
        for (int m = 0; m < 3; ++m)
#pragma unroll
            for (int n = 0; n < 4; ++n)
                acc[m][n] = __builtin_amdgcn_mfma_f32_16x16x32_f16(a[m], bb[n], acc[m][n], 0, 0, 0);
    }
    long pe[4];
#pragma unroll
    for (int n = 0; n < 4; ++n) {
        long p = p0 + n * 16 + fr;
        long q = p / 80; pe[n] = q * LT_ROW + (p - q * 80);
    }
#pragma unroll
    for (int m = 0; m < 3; ++m)
#pragma unroll
        for (int i = 0; i < 4; ++i) {
            int o = wv * 48 + m * 16 + fg * 4 + i;
            long oadr = xb + ((o < 192) ? (long)o * 80 : (long)(o - 192) * 80 + LT_PART);
#pragma unroll
            for (int n = 0; n < 4; ++n) out[oadr + pe[n]] = (half_t)acc[m][n][i];
        }
}

// ================= K1BIG: row-DFT GEMM, zero LDS, zero in-loop barriers ======
template<int NF, int NORM, int OUT16, int K>
__global__ __launch_bounds__(256) void k1big(
    const float* __restrict__ A, long aBatch, long aC, long aRow, int aSplit, long aHiOff,
    const half_t* __restrict__ Bt,
    void* __restrict__ outv, long oBatch, long oC, long oRow, int oSplit, long oHiOff,
    float* __restrict__ inv) {
    const int t = threadIdx.x;
    const long ab = (long)blockIdx.y * aBatch + (long)blockIdx.x * aC;
    const long ob = (long)blockIdx.y * oBatch + (long)blockIdx.x * oC;
    const int lane = t & 63, wv = t >> 6;
    const int fr = lane & 15, fg = lane >> 4;
    constexpr int NFR = NF * 2;
    f32x4 acc[2][NFR];
#pragma unroll
    for (int m = 0; m < 2; ++m)
#pragma unroll
        for (int n = 0; n < NFR; ++n) acc[m][n] = {0.f, 0.f, 0.f, 0.f};
    for (int k0 = 0; k0 < K; k0 += 32) {
        int kk = k0 + fg * 8;
        long ka = (kk < aSplit) ? (long)kk : (long)(kk - aSplit) + aHiOff;
        h8v a[2];
#pragma unroll
        for (int m = 0; m < 2; ++m) {
            const float* g = A + ab + (long)(wv * 32 + m * 16 + fr) * aRow + ka;
            float4 v0 = *(const float4*)g;
            float4 v1 = *(const float4*)(g + 4);
            a[m][0] = (half_t)v0.x; a[m][1] = (half_t)v0.y;
            a[m][2] = (half_t)v0.z; a[m][3] = (half_t)v0.w;
            a[m][4] = (half_t)v1.x; a[m][5] = (half_t)v1.y;
            a[m][6] = (half_t)v1.z; a[m][7] = (half_t)v1.w;
        }
        h8v bb[NFR];
#pragma unroll
        for (int n = 0; n < NFR; ++n)
            bb[n] = *(const h8v*)(Bt + (long)(n * 16 + fr) * K + kk);
#pragma unroll
        for (int m = 0; m < 2; ++m)
#pragma unroll
            for (int n = 0; n < NFR; ++n)
                acc[m][n] = __builtin_amdgcn_mfma_f32_16x16x32_f16(a[m], bb[n], acc[m][n], 0, 0, 0);
    }
#pragma unroll
    for (int m = 0; m < 2; ++m)
#pragma unroll
        for (int i = 0; i < 4; ++i) {
            int r = wv * 32 + m * 16 + fg * 4 + i;
            long rbase = ob + (long)r * oRow;
#pragma unroll
            for (int n = 0; n < NFR; ++n) {
                int j = n * 16 + fr;
                long jm = (j < oSplit) ? (long)j : (long)(j - oSplit) + oHiOff;
                if (OUT16) ((half_t*)outv)[rbase + jm] = (half_t)acc[m][n][i];
                else       ((float*)outv)[rbase + jm]  = acc[m][n][i];
            }
        }
    if (NORM) {
        float ss = 0.f;
#pragma unroll
        for (int m = 0; m < 2; ++m)
#pragma unroll
            for (int n = 0; n < NFR; ++n)
#pragma unroll
                for (int i = 0; i < 4; ++i) ss += acc[m][n][i] * acc[m][n][i];
        __shared__ float red[256];
        red[t] = ss;
        __syncthreads();
        for (int st = 128; st > 0; st >>= 1) {
            if (t < st) red[t] += red[t + st];
            __syncthreads();
        }
        if (t == 0) inv[(long)blockIdx.y * 192 + blockIdx.x] = 1.f / fmaxf(sqrtf(red[0]), 1e-12f);
    }
}

// ---------- depthwise 3x3, pad 1: one block per (channel, batch) plane ----------
__global__ __launch_bounds__(256) void dw3_k(
    const float* __restrict__ in, long inBatch,
    const float* __restrict__ w9,
    float* __restrict__ out, long outBatch,
    int normCnt, float* __restrict__ inv) {
    const int c = blockIdx.x, b = blockIdx.y;
    const int t = threadIdx.x;
    const float* ip = in + (long)b * inBatch + (long)c * HW;
    float* op = out + (long)b * outBatch + (long)c * HW;
    const float* wp = w9 + c * 9;
    const float w0 = wp[0], w1 = wp[1], w2 = wp[2];
    const float w3 = wp[3], w4 = wp[4], w5 = wp[5];
    const float w6 = wp[6], w7 = wp[7], w8 = wp[8];
    const int tx = t & 31;
    const int x0 = tx * 4;
    const int y0 = (t >> 5) * 16;
    const bool lx = (tx > 0), rx = (tx < 31);
    float Ar[6], Br[6], Cr[6];
#define LOADROW(Y, R) do { \
        const float* _p = ip + (Y) * 128 + x0; \
        float4 _v = *(const float4*)_p; \
        R[1] = _v.x; R[2] = _v.y; R[3] = _v.z; R[4] = _v.w; \
        R[0] = lx ? _p[-1] : 0.f; \
        R[5] = rx ? _p[4] : 0.f; } while (0)
    if (y0 == 0) { Ar[0]=Ar[1]=Ar[2]=Ar[3]=Ar[4]=Ar[5]=0.f; }
    else LOADROW(y0 - 1, Ar);
    LOADROW(y0, Br);
    float ss = 0.f;
#pragma unroll
    for (int i = 0; i < 16; ++i) {
        int y = y0 + i;
        if (y + 1 < 128) { LOADROW(y + 1, Cr); }
        else { Cr[0]=Cr[1]=Cr[2]=Cr[3]=Cr[4]=Cr[5]=0.f; }
        float o0 = Ar[0]*w0 + Ar[1]*w1 + Ar[2]*w2
                 + Br[0]*w3 + Br[1]*w4 + Br[2]*w5
                 + Cr[0]*w6 + Cr[1]*w7 + Cr[2]*w8;
        float o1 = Ar[1]*w0 + Ar[2]*w1 + Ar[3]*w2
                 + Br[1]*w3 + Br[2]*w4 + Br[3]*w5
                 + Cr[1]*w6 + Cr[2]*w7 + Cr[3]*w8;
        float o2 = Ar[2]*w0 + Ar[3]*w1 + Ar[4]*w2
                 + Br[2]*w3 + Br[3]*w4 + Br[4]*w5
                 + Cr[2]*w6 + Cr[3]*w7 + Cr[4]*w8;
        float o3 = Ar[3]*w0 + Ar[4]*w1 + Ar[5]*w2
                 + Br[3]*w3 + Br[4]*w4 + Br[5]*w5
                 + Cr[3]*w6 + Cr[4]*w7 + Cr[5]*w8;
        *(float4*)(op + y * 128 + x0) = make_float4(o0, o1, o2, o3);
        ss += o0*o0 + o1*o1 + o2*o2 + o3*o3;
#pragma unroll
        for (int j = 0; j < 6; ++j) { Ar[j] = Br[j]; Br[j] = Cr[j]; }
    }
#undef LOADROW
    if (normCnt > 0 && c < normCnt) {
        __shared__ float red[256];
        red[t] = ss;
        __syncthreads();
        for (int st = 128; st > 0; st >>= 1) {
            if (t < st) red[t] += red[t + st];
            __syncthreads();
        }
        if (t == 0) inv[(long)b * 192 + c] = 1.f / fmaxf(sqrtf(red[0]), 1e-12f);
    }
}

// ================= fp32 Gram, slice-parallel =================
__global__ __launch_bounds__(576) void gramf_k(
    const float* __restrict__ q, long qB,
    const float* __restrict__ k, long kB,
    float* __restrict__ gp) {
    __shared__ float qs[HD][260];
    __shared__ float ks[HD][260];
    const int bn = blockIdx.x, ls = blockIdx.y;
    const int b = bn >> 3, n = bn & 7;
    const int t = threadIdx.x;
    const int l0 = ls * 256;
    const float* qp = q + (long)b * qB + (long)(n * HD) * HW + l0;
    const float* kp = k + (long)b * kB + (long)(n * HD) * HW + l0;
    for (int idx = t; idx < HD * 64; idx += 576) {
        int row = idx >> 6, c4 = (idx & 63) * 4;
        *(float4*)&qs[row][c4] = *(const float4*)(qp + (long)row * HW + c4);
        *(float4*)&ks[row][c4] = *(const float4*)(kp + (long)row * HW + c4);
    }
    __syncthreads();
    const int d = t / 24, e = t - d * 24;
    float acc = 0.f;
#pragma unroll 8
    for (int j = 0; j < 256; j += 4) {
        float4 a = *(const float4*)&qs[d][j];
        float4 bb = *(const float4*)&ks[e][j];
        acc += a.x * bb.x + a.y * bb.y + a.z * bb.z + a.w * bb.w;
    }
    gp[((long)bn * 576 + t) * GSL + ls] = acc;
}

// ---------- slice-sum + normalize + temperature + softmax ----------
__global__ __launch_bounds__(256) void softmax_k(
    const float* __restrict__ gp, const float* __restrict__ invq,
    const float* __restrict__ invk, const float* __restrict__ temp,
    float* __restrict__ attn) {
    int bn = blockIdx.x;
    int b = bn >> 3, n = bn & 7;
    int t = threadIdx.x;
    __shared__ float sums[576];
    for (int idx = t; idx < 576; idx += 256) {
        const float* g = gp + ((long)bn * 576 + idx) * GSL;
        float s = 0.f;
        for (int i = 0; i < GSL; i += 4) {
            float4 v = *(const float4*)(g + i);
            s += v.x + v.y + v.z + v.w;
        }
        sums[idx] = s;
    }
    __syncthreads();
    int d = t;
    if (d >= HD) return;
    float tt = temp[n];
    float iq = invq[b * 192 + n * HD + d];
    float row[HD];
#pragma unroll
    for (int e = 0; e < HD; ++e)
        row[e] = sums[d * HD + e] * iq * invk[b * 192 + n * HD + e] * tt;
    float m = row[0];
#pragma unroll
    for (int e = 1; e < HD; ++e) m = fmaxf(m, row[e]);
    float ssum = 0.f;
#pragma unroll
    for (int e = 0; e < HD; ++e) { row[e] = expf(row[e] - m); ssum += row[e]; }
    float is = 1.f / ssum;
#pragma unroll
    for (int e = 0; e < HD; ++e) attn[(long)bn * 576 + d * HD + e] = row[e] * is;
}

// ---------- out[d,p] = sum_e attn[d,e] * v[e,p] ----------
__global__ void attnapply_k(const float* __restrict__ attn, const float* __restrict__ v,
                            long vB, float* __restrict__ out, long outB) {
    int p = blockIdx.x * 256 + threadIdx.x;
    int bn = blockIdx.y;
    int b = bn >> 3, n = bn & 7;
    __shared__ float a[576];
    for (int i = threadIdx.x; i < 576; i += 256) a[i] = attn[(long)bn * 576 + i];
    __syncthreads();
    const float* vp = v + (long)b * vB + (long)(n * HD) * HW + p;
    float acc[HD];
#pragma unroll
    for (int d = 0; d < HD; ++d) acc[d] = 0.f;
    for (int e = 0; e < HD; ++e) {
        float vv = vp[(long)e * HW];
#pragma unroll
        for (int d = 0; d < HD; ++d) acc[d] += a[d * HD + e] * vv;
    }
    float* op = out + (long)b * outB + (long)(n * HD) * HW + p;
#pragma unroll
    for (int d = 0; d < HD; ++d) op[(long)d * HW] = acc[d];
}

extern "C" void kernel_launch(void* const* d_in, const int* in_sizes, int n_in,
                              void* d_out, int out_size, void* d_ws, size_t ws_size,
                              hipStream_t stream) {
    const float* x        = (const float*)d_in[0];
    const float* w_qkv1   = (const float*)d_in[1];
    const float* w_qkv1dw = (const float*)d_in[2];
    const float* w_proj1  = (const float*)d_in[3];
    const float* w_fdfp1  = (const float*)d_in[4];
    const float* w_fdfp2  = (const float*)d_in[5];
    const float* w_kv2    = (const float*)d_in[6];
    const float* w_kv2dw  = (const float*)d_in[7];
    const float* w_proj2  = (const float*)d_in[8];
    const float* temp     = (const float*)d_in[9];
    float* out = (float*)d_out;
    float* ws  = (float*)d_ws;
    dim3 blk(256);
    const int BIG = 1 << 20;

    // ---- init: all fp16 weights/bases in one dispatch ----
    init_all_k<<<2688, blk, 0, stream>>>(
        w_qkv1, w_fdfp1, w_fdfp2, w_proj2, w_kv2, w_proj1, ws);

    // ---- fdfp(x) -> q2 (+ fused q2 norms) ----
    k1big<5, 0, 1, 128><<<dim3(192, 4), blk, 0, stream>>>(
        x, XB, (long)HW, 128L, BIG, 0L,
        (const half_t*)(ws + H_B1T),
        (void*)(ws + CB0), LT_B, (long)FP, LT_ROW, 80, LT_PART, nullptr);
    k2big<1, 1><<<dim3(240, 4), blk, 0, stream>>>(
        (const half_t*)(ws + H_B2), (const void*)(ws + CB0), (void*)(ws + CB1));
    kff4h<<<dim3(160, 4), 512, 0, stream>>>(
        (const half_t*)(ws + H_W1), (const half_t*)(ws + H_W2),
        (const half_t*)(ws + CB1), (half_t*)(ws + CB0));
    k2big<1, 0><<<dim3(240, 4), blk, 0, stream>>>(
        (const half_t*)(ws + H_B3), (const void*)(ws + CB0), (void*)(ws + CB1));
    k1big<4, 1, 0, 160><<<dim3(192, 4), blk, 0, stream>>>(
        ws + CB1, LT_B, (long)FP, LT_ROW, 80, LT_PART,
        (const half_t*)(ws + H_B4T),
        (void*)(ws + OFF_Q2), XB, (long)HW, 128L, BIG, 0L, ws + SM_INVQ2);

    // ---- stage 1: qkv = dw3(kcv(x)) in 3 chunks (+ fused q1/k1 norms) ----
    for (int ch = 0; ch < 3; ++ch) {
        kcv<4><<<dim3(256, 4), 256, 0, stream>>>(
            (const half_t*)(ws + H_WQKV) + (long)ch * 192 * 192,
            x, XB, ws + OFF_T1, XB);
        dw3_k<<<dim3(192, 4), blk, 0, stream>>>(
            ws + OFF_T1, XB, w_qkv1dw + ch * 192 * 9,
            ws + (long)ch * 192 * HW, (long)576 * HW,
            ch == 2 ? 0 : 192,
            ch == 0 ? ws + SM_INVQ1 : ws + SM_INVK1);
    }
    // stage-1 partials at OFF_T1: qkv [0..37.7M) live, OFF_T1 [37.7M..] free.
    gramf_k<<<dim3(32, GSL), 576, 0, stream>>>(
        ws, (long)576 * HW, ws + (long)192 * HW, (long)576 * HW, ws + OFF_T1);
    softmax_k<<<32, blk, 0, stream>>>(ws + OFF_T1, ws + SM_INVQ1, ws + SM_INVK1, temp, ws + SM_ATT);
    attnapply_k<<<dim3(64, 32), blk, 0, stream>>>(
        ws + SM_ATT, ws + (long)384 * HW, (long)576 * HW, ws + OFF_T1, XB);

    // ---- kv2 = dw3(kcv(out1, Wf)) (+ fused k2 norms) ----
    kcv<8><<<dim3(256, 4), 512, 0, stream>>>(
        (const half_t*)(ws + H_WF), ws + OFF_T1, XB, ws + OFF_KT, (long)384 * HW);
    dw3_k<<<dim3(384, 4), blk, 0, stream>>>(
        ws + OFF_KT, (long)384 * HW, w_kv2dw, ws + OFF_KF, (long)384 * HW,
        192, ws + SM_INVK2);

    // ---- stage 2 attention ----
    // partials at ws[0..1.18M): kv2 pre-dw tmp region, dead after dw3.
    // (NOT OFF_T1 — that aliases kv2 batch 2, the r6-r8 corruption.)
    gramf_k<<<dim3(32, GSL), 576, 0, stream>>>(
        ws + OFF_Q2, XB, ws + OFF_KF, (long)384 * HW, ws + OFF_KT);
    softmax_k<<<32, blk, 0, stream>>>(ws + OFF_KT, ws + SM_INVQ2, ws + SM_INVK2, temp, ws + SM_ATT);
    attnapply_k<<<dim3(64, 32), blk, 0, stream>>>(
        ws + SM_ATT, ws + OFF_KF + (long)192 * HW, (long)384 * HW, ws + OFF_O2, XB);
    kcv<4><<<dim3(256, 4), 256, 0, stream>>>(
        (const half_t*)(ws + H_PRJ), ws + OFF_O2, XB, out, XB);
}